// Round 2
// baseline (3195.086 us; speedup 1.0000x reference)
//
#include <hip/hip_runtime.h>
#include <math.h>

// Problem constants
#define B_  2
#define S_  2048
#define H_  2048
#define NH_ 16
#define HD_ 128
#define L_  512
// ROT = 1024, rope uses first 512 cos/sin columns only.

// ---------------------------------------------------------------------------
// Generic fp32 GEMM:  C[m, c0+n] = sum_k A[m,k] * W[n,k] + bias[n]
// A: (M,K) row-major, W: (N,K) row-major (i.e. C = A @ W^T + b)
// Tiles: BM x BN, K-step 16, 256 threads, per-thread TM x TN register tile.
// ---------------------------------------------------------------------------
template<int BM, int BN, int TM, int TN>
__global__ __launch_bounds__(256)
void gemm_bias_kernel(const float* __restrict__ A, const float* __restrict__ W,
                      const float* __restrict__ bias, float* __restrict__ C,
                      int M, int N, int K, int ldc, int c0)
{
    constexpr int KT   = 16;
    constexpr int TNB  = BN / TN;            // threads along n (=16)
    constexpr int SA   = BM + 8;             // LDS row stride (16B aligned)
    constexpr int SB   = BN + 8;

    __shared__ float As[KT * SA];            // As[k][m]  (transposed tile)
    __shared__ float Ws[KT * SB];            // Ws[k][n]

    const int tid = threadIdx.x;
    const int tn  = tid % TNB;
    const int tm  = tid / TNB;
    const int m0  = blockIdx.y * BM;
    const int n0  = blockIdx.x * BN;

    float acc[TM][TN];
#pragma unroll
    for (int i = 0; i < TM; ++i)
#pragma unroll
        for (int j = 0; j < TN; ++j) acc[i][j] = 0.0f;

    for (int k0 = 0; k0 < K; k0 += KT) {
        __syncthreads();
        // ---- stage A tile (BM x 16) transposed into LDS ----
#pragma unroll
        for (int it = 0; it < (BM * 4) / 256; ++it) {
            const int e   = tid + it * 256;      // float4 index
            const int row = e >> 2;
            const int c4  = (e & 3) * 4;
            const float4 v = *reinterpret_cast<const float4*>(
                &A[(size_t)(m0 + row) * K + k0 + c4]);
            As[(c4 + 0) * SA + row] = v.x;
            As[(c4 + 1) * SA + row] = v.y;
            As[(c4 + 2) * SA + row] = v.z;
            As[(c4 + 3) * SA + row] = v.w;
        }
        // ---- stage W tile (BN x 16) transposed into LDS ----
#pragma unroll
        for (int it = 0; it < (BN * 4) / 256; ++it) {
            const int e   = tid + it * 256;
            const int row = e >> 2;
            const int c4  = (e & 3) * 4;
            const float4 v = *reinterpret_cast<const float4*>(
                &W[(size_t)(n0 + row) * K + k0 + c4]);
            Ws[(c4 + 0) * SB + row] = v.x;
            Ws[(c4 + 1) * SB + row] = v.y;
            Ws[(c4 + 2) * SB + row] = v.z;
            Ws[(c4 + 3) * SB + row] = v.w;
        }
        __syncthreads();

#pragma unroll
        for (int kk = 0; kk < KT; ++kk) {
            float a[TM], bb[TN];
#pragma unroll
            for (int i = 0; i < TM; i += 4)
                *reinterpret_cast<float4*>(&a[i]) =
                    *reinterpret_cast<const float4*>(&As[kk * SA + tm * TM + i]);
#pragma unroll
            for (int j = 0; j < TN; j += 4)
                *reinterpret_cast<float4*>(&bb[j]) =
                    *reinterpret_cast<const float4*>(&Ws[kk * SB + tn * TN + j]);
#pragma unroll
            for (int i = 0; i < TM; ++i)
#pragma unroll
                for (int j = 0; j < TN; ++j)
                    acc[i][j] += a[i] * bb[j];
        }
    }

    // ---- epilogue: bias add + store ----
#pragma unroll
    for (int i = 0; i < TM; ++i) {
        const int row = m0 + tm * TM + i;
#pragma unroll
        for (int j = 0; j < TN; j += 4) {
            const int col = n0 + tn * TN + j;
            float4 o;
            o.x = acc[i][j + 0] + bias[col + 0];
            o.y = acc[i][j + 1] + bias[col + 1];
            o.z = acc[i][j + 2] + bias[col + 2];
            o.w = acc[i][j + 3] + bias[col + 3];
            *reinterpret_cast<float4*>(&C[(size_t)row * ldc + c0 + col]) = o;
        }
    }
}

// ---------------------------------------------------------------------------
// RoPE (in place on cols [1024,2048) of k buffer). grid = (B*S, 2), 256 thr.
// out[d]     = x1*cos - x2*sin ;  out[512+d] = x1*sin + x2*cos,  d in [0,512)
// angle(pos,d) = pos * 10000^(-d/512)
// ---------------------------------------------------------------------------
__global__ void rope_kernel(float* __restrict__ kbuf)
{
    const int row = blockIdx.x;                        // 0..B*S-1
    const int d   = blockIdx.y * 256 + threadIdx.x;    // 0..511
    const int pos = row & (S_ - 1);                    // s index
    // ln(10000)/512 = 0.017988945...
    const float inv  = expf((float)d * -0.017988946f);
    const float ang  = (float)pos * inv;
    const float c = cosf(ang), s = sinf(ang);
    float* p = kbuf + (size_t)row * H_ + 1024;
    const float x1 = p[d];
    const float x2 = p[d + 512];
    p[d]       = x1 * c - x2 * s;
    p[d + 512] = x1 * s + x2 * c;
}

// ---------------------------------------------------------------------------
// Flash attention (fp32). One block = one (b,h) x 64-row Q tile.
// 256 threads = 16x16 grid, per-thread 4x4 score tile / 4x8 output tile.
// LDS: Qt[128][68] Kt[128][68] (d-major, transposed), Vs[64][132], P[64][65]
// Dynamic LDS = 120064 B (needs hipFuncSetAttribute).
// ---------------------------------------------------------------------------
__global__ __launch_bounds__(256)
void attn_kernel(const float* __restrict__ Q, const float* __restrict__ K,
                 const float* __restrict__ V, float* __restrict__ O)
{
    extern __shared__ float smem[];
    float* Qt = smem;                 // 128*68
    float* Kt = Qt + 128 * 68;        // 128*68
    float* Vs = Kt + 128 * 68;        // 64*132
    float* Pl = Vs + 64 * 132;        // 64*65

    const int tid = threadIdx.x;
    const int tn  = tid & 15;
    const int tm  = tid >> 4;
    const int bh  = blockIdx.y;            // 0..31
    const int b   = bh >> 4;
    const int h   = bh & 15;
    const int q0  = blockIdx.x * 64;

    const float scale = 0.08838834764831845f;  // 1/sqrt(128)
    const float* qp = Q + (size_t)(b * S_ + q0) * H_ + h * HD_;
    const float* kp = K + (size_t)(b * S_) * H_ + h * HD_;
    const float* vp = V + (size_t)(b * S_) * H_ + h * HD_;

    // ---- load Q tile (64 x 128), scaled, transposed to d-major ----
#pragma unroll
    for (int it = 0; it < 8; ++it) {
        const int e  = tid + it * 256;
        const int r  = e >> 5;
        const int d4 = (e & 31) * 4;
        const float4 v = *reinterpret_cast<const float4*>(&qp[(size_t)r * H_ + d4]);
        Qt[(d4 + 0) * 68 + r] = v.x * scale;
        Qt[(d4 + 1) * 68 + r] = v.y * scale;
        Qt[(d4 + 2) * 68 + r] = v.z * scale;
        Qt[(d4 + 3) * 68 + r] = v.w * scale;
    }

    float m_run[4], l_run[4], o_acc[4][8];
#pragma unroll
    for (int i = 0; i < 4; ++i) {
        m_run[i] = -INFINITY;
        l_run[i] = 0.0f;
#pragma unroll
        for (int j = 0; j < 8; ++j) o_acc[i][j] = 0.0f;
    }

    for (int kt = 0; kt < S_ / 64; ++kt) {
        __syncthreads();   // previous iteration done with Kt/Vs/Pl (also Q vis)
        const float* kpt = kp + (size_t)(kt * 64) * H_;
        const float* vpt = vp + (size_t)(kt * 64) * H_;
#pragma unroll
        for (int it = 0; it < 8; ++it) {
            const int e  = tid + it * 256;
            const int r  = e >> 5;
            const int d4 = (e & 31) * 4;
            const float4 kv = *reinterpret_cast<const float4*>(&kpt[(size_t)r * H_ + d4]);
            Kt[(d4 + 0) * 68 + r] = kv.x;
            Kt[(d4 + 1) * 68 + r] = kv.y;
            Kt[(d4 + 2) * 68 + r] = kv.z;
            Kt[(d4 + 3) * 68 + r] = kv.w;
            const float4 vv = *reinterpret_cast<const float4*>(&vpt[(size_t)r * H_ + d4]);
            *reinterpret_cast<float4*>(&Vs[r * 132 + d4]) = vv;
        }
        __syncthreads();

        // ---- S tile (64x64) = Q_tile @ K_tile^T (scale folded into Q) ----
        float s_acc[4][4];
#pragma unroll
        for (int i = 0; i < 4; ++i)
#pragma unroll
            for (int j = 0; j < 4; ++j) s_acc[i][j] = 0.0f;

#pragma unroll 8
        for (int d = 0; d < HD_; ++d) {
            const float4 a  = *reinterpret_cast<const float4*>(&Qt[d * 68 + tm * 4]);
            const float4 bb = *reinterpret_cast<const float4*>(&Kt[d * 68 + tn * 4]);
            const float av[4] = {a.x, a.y, a.z, a.w};
            const float bv[4] = {bb.x, bb.y, bb.z, bb.w};
#pragma unroll
            for (int i = 0; i < 4; ++i)
#pragma unroll
                for (int j = 0; j < 4; ++j)
                    s_acc[i][j] += av[i] * bv[j];
        }

        // ---- online softmax (rows split across 16 tn lanes) ----
#pragma unroll
        for (int i = 0; i < 4; ++i) {
            float mx = fmaxf(fmaxf(s_acc[i][0], s_acc[i][1]),
                             fmaxf(s_acc[i][2], s_acc[i][3]));
            mx = fmaxf(mx, __shfl_xor(mx, 1));
            mx = fmaxf(mx, __shfl_xor(mx, 2));
            mx = fmaxf(mx, __shfl_xor(mx, 4));
            mx = fmaxf(mx, __shfl_xor(mx, 8));
            const float mnew = fmaxf(m_run[i], mx);
            const float f    = __expf(m_run[i] - mnew);
            float p[4], ls = 0.0f;
#pragma unroll
            for (int j = 0; j < 4; ++j) {
                p[j] = __expf(s_acc[i][j] - mnew);
                ls += p[j];
            }
            ls += __shfl_xor(ls, 1);
            ls += __shfl_xor(ls, 2);
            ls += __shfl_xor(ls, 4);
            ls += __shfl_xor(ls, 8);
            l_run[i] = l_run[i] * f + ls;
            m_run[i] = mnew;
#pragma unroll
            for (int j = 0; j < 8; ++j) o_acc[i][j] *= f;
            const int prow = (tm * 4 + i) * 65 + tn * 4;
#pragma unroll
            for (int j = 0; j < 4; ++j) Pl[prow + j] = p[j];
        }
        __syncthreads();

        // ---- O += P @ V_tile ----
#pragma unroll 4
        for (int kk = 0; kk < 64; ++kk) {
            float pv[4];
#pragma unroll
            for (int i = 0; i < 4; ++i) pv[i] = Pl[(tm * 4 + i) * 65 + kk];
            const float4 v0 = *reinterpret_cast<const float4*>(&Vs[kk * 132 + tn * 8]);
            const float4 v1 = *reinterpret_cast<const float4*>(&Vs[kk * 132 + tn * 8 + 4]);
#pragma unroll
            for (int i = 0; i < 4; ++i) {
                o_acc[i][0] += pv[i] * v0.x;
                o_acc[i][1] += pv[i] * v0.y;
                o_acc[i][2] += pv[i] * v0.z;
                o_acc[i][3] += pv[i] * v0.w;
                o_acc[i][4] += pv[i] * v1.x;
                o_acc[i][5] += pv[i] * v1.y;
                o_acc[i][6] += pv[i] * v1.z;
                o_acc[i][7] += pv[i] * v1.w;
            }
        }
    }

    // ---- normalize + store ----
    float* op = O + (size_t)(b * S_ + q0) * H_ + h * HD_;
#pragma unroll
    for (int i = 0; i < 4; ++i) {
        const float inv_l = 1.0f / l_run[i];
        const int row = tm * 4 + i;
        float4 o0, o1;
        o0.x = o_acc[i][0] * inv_l; o0.y = o_acc[i][1] * inv_l;
        o0.z = o_acc[i][2] * inv_l; o0.w = o_acc[i][3] * inv_l;
        o1.x = o_acc[i][4] * inv_l; o1.y = o_acc[i][5] * inv_l;
        o1.z = o_acc[i][6] * inv_l; o1.w = o_acc[i][7] * inv_l;
        *reinterpret_cast<float4*>(&op[(size_t)row * H_ + tn * 8])     = o0;
        *reinterpret_cast<float4*>(&op[(size_t)row * H_ + tn * 8 + 4]) = o1;
    }
}

// ---------------------------------------------------------------------------
// Launch
// ---------------------------------------------------------------------------
extern "C" void kernel_launch(void* const* d_in, const int* in_sizes, int n_in,
                              void* d_out, int out_size, void* d_ws, size_t ws_size,
                              hipStream_t stream)
{
    const float* hs       = (const float*)d_in[0];
    const float* Wq_down  = (const float*)d_in[1];
    const float* bq_down  = (const float*)d_in[2];
    const float* Wkv_down = (const float*)d_in[3];
    const float* bkv_down = (const float*)d_in[4];
    const float* Wq_up    = (const float*)d_in[5];
    const float* bq_up    = (const float*)d_in[6];
    const float* Wk_nope  = (const float*)d_in[7];
    const float* bk_nope  = (const float*)d_in[8];
    const float* Wk_rope  = (const float*)d_in[9];
    const float* bk_rope  = (const float*)d_in[10];
    const float* Wv_up    = (const float*)d_in[11];
    const float* bv_up    = (const float*)d_in[12];
    const float* Wo       = (const float*)d_in[13];
    const float* bo       = (const float*)d_in[14];
    float* out = (float*)d_out;

    // Workspace layout (floats). Total = 37,748,736 floats = 144 MB.
    float* ws     = (float*)d_ws;
    float* lat_q  = ws;                         // 4096 x 512
    float* lat_kv = lat_q  + (size_t)4096 * 512;
    float* qb     = lat_kv + (size_t)4096 * 512;  // 4096 x 2048
    float* kb     = qb     + (size_t)4096 * 2048;
    float* vb     = kb     + (size_t)4096 * 2048;
    float* ob     = vb     + (size_t)4096 * 2048;

    const int M = B_ * S_;   // 4096

    // 1,2: latent down-projections  (M x 512, K=2048)
    gemm_bias_kernel<128, 64, 8, 4><<<dim3(512 / 64, M / 128), 256, 0, stream>>>(
        hs, Wq_down, bq_down, lat_q, M, 512, 2048, 512, 0);
    gemm_bias_kernel<128, 64, 8, 4><<<dim3(512 / 64, M / 128), 256, 0, stream>>>(
        hs, Wkv_down, bkv_down, lat_kv, M, 512, 2048, 512, 0);

    // 3: q up-projection (M x 2048, K=512)
    gemm_bias_kernel<128, 128, 8, 8><<<dim3(2048 / 128, M / 128), 256, 0, stream>>>(
        lat_q, Wq_up, bq_up, qb, M, 2048, 512, 2048, 0);

    // 4,5: k_nope -> kb[:, :1024], k_rope(pre) -> kb[:, 1024:]
    gemm_bias_kernel<128, 128, 8, 8><<<dim3(1024 / 128, M / 128), 256, 0, stream>>>(
        lat_kv, Wk_nope, bk_nope, kb, M, 1024, 512, 2048, 0);
    gemm_bias_kernel<128, 128, 8, 8><<<dim3(1024 / 128, M / 128), 256, 0, stream>>>(
        lat_kv, Wk_rope, bk_rope, kb, M, 1024, 512, 2048, 1024);

    // 6: rotary on kb[:, 1024:2048]
    rope_kernel<<<dim3(M, 2), 256, 0, stream>>>(kb);

    // 7: v up-projection
    gemm_bias_kernel<128, 128, 8, 8><<<dim3(2048 / 128, M / 128), 256, 0, stream>>>(
        lat_kv, Wv_up, bv_up, vb, M, 2048, 512, 2048, 0);

    // 8: flash attention -> ob
    const int attn_lds = (128 * 68 * 2 + 64 * 132 + 64 * 65) * 4;  // 120064 B
    hipFuncSetAttribute(reinterpret_cast<const void*>(attn_kernel),
                        hipFuncAttributeMaxDynamicSharedMemorySize, attn_lds);
    attn_kernel<<<dim3(S_ / 64, B_ * NH_), 256, attn_lds, stream>>>(qb, kb, vb, ob);

    // 9: output projection -> d_out
    gemm_bias_kernel<128, 128, 8, 8><<<dim3(2048 / 128, M / 128), 256, 0, stream>>>(
        ob, Wo, bo, out, M, 2048, 2048, 2048, 0);
}

// Round 3
// 669.266 us; speedup vs baseline: 4.7740x; 4.7740x over previous
//
#include <hip/hip_runtime.h>
#include <math.h>

#define B_  2
#define S_  2048
#define H_  2048
#define NH_ 16
#define HD_ 128

typedef __attribute__((ext_vector_type(8))) short short8;
typedef __attribute__((ext_vector_type(4))) float f32x4;

#define AS1 __attribute__((address_space(1)))
#define AS3 __attribute__((address_space(3)))

__device__ __forceinline__ ushort f2bf(float f) {
    union { float f; unsigned u; } x; x.f = f;
    unsigned r = (x.u + 0x7FFF + ((x.u >> 16) & 1)) >> 16;
    return (ushort)r;
}
__device__ __forceinline__ float bf2f(ushort u) {
    union { unsigned u; float f; } x; x.u = ((unsigned)u) << 16;
    return x.f;
}
__device__ __forceinline__ void gload_lds16(const void* g, void* l) {
    __builtin_amdgcn_global_load_lds((const AS1 void*)g, (AS3 void*)l, 16, 0, 0);
}

// ---------------------------------------------------------------------------
// fp32 -> bf16 cast
// ---------------------------------------------------------------------------
__global__ void cast_bf(const float* __restrict__ in, ushort* __restrict__ out, int n)
{
    int i = (blockIdx.x * 256 + threadIdx.x) * 4;
    if (i >= n) return;
    float4 v = *reinterpret_cast<const float4*>(in + i);
    ushort4 o;
    o.x = f2bf(v.x); o.y = f2bf(v.y); o.z = f2bf(v.z); o.w = f2bf(v.w);
    *reinterpret_cast<ushort4*>(out + i) = o;
}

// ---------------------------------------------------------------------------
// bf16 MFMA GEMM: C[m, c0+n] = sum_k A[m,k]*W[n,k] + bias[n]
// A (M,K) bf16 row-major, W (N,K) bf16 row-major. 128x128 tile, BK=32,
// 4 waves (2x2), each wave 64x64 = 4x4 fragments of 16x16x32.
// OUT_BF16: 1 -> ushort bf16 C, 0 -> float C.
// ---------------------------------------------------------------------------
template<int OUT_BF16>
__global__ __launch_bounds__(256)
void gemm_mfma(const ushort* __restrict__ A, const ushort* __restrict__ W,
               const float* __restrict__ bias, void* __restrict__ Cv,
               int M, int N, int K, int ldc, int c0)
{
    __shared__ ushort Asm[128 * 32];
    __shared__ ushort Bsm[128 * 32];

    const int tid  = threadIdx.x;
    const int w    = tid >> 6;
    const int lane = tid & 63;
    const int lo   = lane & 15;
    const int hi   = lane >> 4;
    const int wm   = w >> 1;
    const int wn   = w & 1;
    const int m0   = blockIdx.y * 128;
    const int n0   = blockIdx.x * 128;

    const int l4 = lane >> 2;   // row within 16-row staging group
    const int s4 = lane & 3;    // 16B slot within 64B row

    f32x4 acc[4][4];
#pragma unroll
    for (int i = 0; i < 4; ++i)
#pragma unroll
        for (int j = 0; j < 4; ++j) acc[i][j] = f32x4{0.f, 0.f, 0.f, 0.f};

    for (int k0 = 0; k0 < K; k0 += 32) {
        __syncthreads();
#pragma unroll
        for (int t = 0; t < 2; ++t) {
            const int row = w * 32 + t * 16 + l4;
            gload_lds16(A + (size_t)(m0 + row) * K + k0 + s4 * 8,
                        (char*)Asm + w * 2048 + t * 1024);
            gload_lds16(W + (size_t)(n0 + row) * K + k0 + s4 * 8,
                        (char*)Bsm + w * 2048 + t * 1024);
        }
        __syncthreads();

        short8 a[4], b[4];
#pragma unroll
        for (int i = 0; i < 4; ++i)
            a[i] = *reinterpret_cast<const short8*>(&Asm[(wm * 64 + i * 16 + lo) * 32 + hi * 8]);
#pragma unroll
        for (int j = 0; j < 4; ++j)
            b[j] = *reinterpret_cast<const short8*>(&Bsm[(wn * 64 + j * 16 + lo) * 32 + hi * 8]);
#pragma unroll
        for (int i = 0; i < 4; ++i)
#pragma unroll
            for (int j = 0; j < 4; ++j)
                acc[i][j] = __builtin_amdgcn_mfma_f32_16x16x32_bf16(a[i], b[j], acc[i][j], 0, 0, 0);
    }

    // epilogue
#pragma unroll
    for (int i = 0; i < 4; ++i) {
#pragma unroll
        for (int j = 0; j < 4; ++j) {
            const int col = n0 + wn * 64 + j * 16 + lo;
            const float bv = bias[col];
#pragma unroll
            for (int r = 0; r < 4; ++r) {
                const int row = m0 + wm * 64 + i * 16 + hi * 4 + r;
                const float v = acc[i][j][r] + bv;
                if (OUT_BF16)
                    ((ushort*)Cv)[(size_t)row * ldc + c0 + col] = f2bf(v);
                else
                    ((float*)Cv)[(size_t)row * ldc + c0 + col] = v;
            }
        }
    }
}

// ---------------------------------------------------------------------------
// RoPE: read pre-rotary k_rope (bf16, [4096][1024]), write rotated bf16 into
// kb cols [1024,2048). grid (4096, 2) x 256.
// ---------------------------------------------------------------------------
__global__ void rope_bf(const ushort* __restrict__ pre, ushort* __restrict__ kb)
{
    const int row = blockIdx.x;
    const int d   = blockIdx.y * 256 + threadIdx.x;   // 0..511
    const int pos = row & (S_ - 1);
    const float inv = expf((float)d * -0.017988946f); // ln(10000)/512
    const float ang = (float)pos * inv;
    const float c = cosf(ang), s = sinf(ang);
    const float x1 = bf2f(pre[(size_t)row * 1024 + d]);
    const float x2 = bf2f(pre[(size_t)row * 1024 + 512 + d]);
    kb[(size_t)row * 2048 + 1024 + d]       = f2bf(x1 * c - x2 * s);
    kb[(size_t)row * 2048 + 1024 + 512 + d] = f2bf(x1 * s + x2 * c);
}

// ---------------------------------------------------------------------------
// V transpose: vb [4096][2048] bf16 -> vt [32 bh][128 d][2048 tok]
// grid (32 s-tiles, 32 bh) x 256.
// ---------------------------------------------------------------------------
__global__ __launch_bounds__(256)
void transpose_v(const ushort* __restrict__ vb, ushort* __restrict__ vt)
{
    __shared__ ushort tile[64][136];
    const int tid = threadIdx.x;
    const int bh  = blockIdx.y;
    const int b   = bh >> 4;
    const int h   = bh & 15;
    const int s0  = blockIdx.x * 64;

#pragma unroll
    for (int r = 0; r < 4; ++r) {
        const int c   = r * 256 + tid;     // 0..1023
        const int row = c >> 4;
        const int col = (c & 15) * 8;
        short8 v = *reinterpret_cast<const short8*>(
            vb + (size_t)(b * S_ + s0 + row) * H_ + h * HD_ + col);
        *reinterpret_cast<short8*>(&tile[row][col]) = v;
    }
    __syncthreads();
#pragma unroll
    for (int r = 0; r < 4; ++r) {
        const int c   = r * 256 + tid;     // 0..1023
        const int d   = c >> 3;
        const int tok = (c & 7) * 8;
        short8 vv;
#pragma unroll
        for (int j = 0; j < 8; ++j) vv[j] = (short)tile[tok + j][d];
        *reinterpret_cast<short8*>(vt + ((size_t)bh * 128 + d) * S_ + s0 + tok) = vv;
    }
}

// ---------------------------------------------------------------------------
// Flash attention, bf16 MFMA. Block = 64 q-rows for one (b,h); 4 waves,
// each wave owns 16 q-rows. KV tile = 64. K LDS XOR-swizzled; Vt LDS padded
// to 72 bf16/row; P staged via padded LDS.
// ---------------------------------------------------------------------------
__global__ __launch_bounds__(256)
void attn_mfma(const ushort* __restrict__ Q, const ushort* __restrict__ K,
               const ushort* __restrict__ Vt, ushort* __restrict__ O)
{
    __shared__ ushort Kl[64 * 128];   // swizzled rows of 256B
    __shared__ ushort Vl[128 * 72];   // [d][k] padded
    __shared__ ushort Pl[4 * 16 * 72];

    const int tid  = threadIdx.x;
    const int w    = tid >> 6;
    const int lane = tid & 63;
    const int lo   = lane & 15;
    const int hi   = lane >> 4;
    const int bh   = blockIdx.y;
    const int b    = bh >> 4;
    const int q0   = blockIdx.x * 64;
    const size_t headoff = (size_t)(bh & 15) * HD_;
    const float scale = 0.08838834764831845f;

    // Q fragments in registers (A-operand: lane lo = q-row, hi*8 = d-group)
    const int q = q0 + w * 16 + lo;
    const ushort* qrow = Q + (size_t)(b * S_ + q) * H_ + headoff;
    short8 aq[4];
#pragma unroll
    for (int kd = 0; kd < 4; ++kd)
        aq[kd] = *reinterpret_cast<const short8*>(qrow + kd * 32 + hi * 8);

    f32x4 oacc[8];
#pragma unroll
    for (int fd = 0; fd < 8; ++fd) oacc[fd] = f32x4{0.f, 0.f, 0.f, 0.f};
    float m_run[4], l_run[4];
#pragma unroll
    for (int r = 0; r < 4; ++r) { m_run[r] = -INFINITY; l_run[r] = 0.f; }

    const ushort* kbase = K  + (size_t)(b * S_) * H_ + headoff;
    const ushort* vbase = Vt + (size_t)bh * 128 * S_;

    for (int kt = 0; kt < S_ / 64; ++kt) {
        __syncthreads();
        // ---- stage K tile (64x128, swizzled) ----
#pragma unroll
        for (int r = 0; r < 4; ++r) {
            const int c    = r * 256 + tid;       // 0..1023 16B chunks
            const int key  = c >> 4;
            const int slot = c & 15;
            short8 v = *reinterpret_cast<const short8*>(
                kbase + (size_t)(kt * 64 + key) * H_ + slot * 8);
            const int addr = key * 256 + ((slot * 16) ^ ((key & 7) << 4));
            *reinterpret_cast<short8*>((char*)Kl + addr) = v;
        }
        // ---- stage Vt tile (128 d x 64 k, padded) ----
#pragma unroll
        for (int r = 0; r < 4; ++r) {
            const int c    = r * 256 + tid;
            const int d    = c >> 3;
            const int slot = c & 7;
            short8 v = *reinterpret_cast<const short8*>(
                vbase + (size_t)d * S_ + kt * 64 + slot * 8);
            *reinterpret_cast<short8*>((char*)Vl + d * 144 + slot * 16) = v;
        }
        __syncthreads();

        // ---- S = Q K^T  (16q x 64k per wave) ----
        f32x4 s[4];
#pragma unroll
        for (int fn = 0; fn < 4; ++fn) {
            f32x4 a = f32x4{0.f, 0.f, 0.f, 0.f};
            const int key = fn * 16 + lo;
#pragma unroll
            for (int kd = 0; kd < 4; ++kd) {
                const int addr = key * 256 + ((kd * 64 + hi * 16) ^ ((key & 7) << 4));
                short8 bk = *reinterpret_cast<const short8*>((const char*)Kl + addr);
                a = __builtin_amdgcn_mfma_f32_16x16x32_bf16(aq[kd], bk, a, 0, 0, 0);
            }
            s[fn] = a;
        }

        // ---- online softmax ----
        float f_r[4];
#pragma unroll
        for (int r = 0; r < 4; ++r) {
            float sv[4];
#pragma unroll
            for (int fn = 0; fn < 4; ++fn) sv[fn] = s[fn][r] * scale;
            float mx = fmaxf(fmaxf(sv[0], sv[1]), fmaxf(sv[2], sv[3]));
            mx = fmaxf(mx, __shfl_xor(mx, 1));
            mx = fmaxf(mx, __shfl_xor(mx, 2));
            mx = fmaxf(mx, __shfl_xor(mx, 4));
            mx = fmaxf(mx, __shfl_xor(mx, 8));
            const float mnew = fmaxf(m_run[r], mx);
            const float f = __expf(m_run[r] - mnew);
            m_run[r] = mnew;
            float ls = 0.f;
            ushort pb[4];
#pragma unroll
            for (int fn = 0; fn < 4; ++fn) {
                const float p = __expf(sv[fn] - mnew);
                ls += p;
                pb[fn] = f2bf(p);
            }
            ls += __shfl_xor(ls, 1);
            ls += __shfl_xor(ls, 2);
            ls += __shfl_xor(ls, 4);
            ls += __shfl_xor(ls, 8);
            l_run[r] = l_run[r] * f + ls;
            f_r[r] = f;
#pragma unroll
            for (int fn = 0; fn < 4; ++fn)
                Pl[w * 1152 + (hi * 4 + r) * 72 + fn * 16 + lo] = pb[fn];
        }
#pragma unroll
        for (int fd = 0; fd < 8; ++fd)
#pragma unroll
            for (int r = 0; r < 4; ++r) oacc[fd][r] *= f_r[r];

        // ---- O += P V ----
#pragma unroll
        for (int ks = 0; ks < 2; ++ks) {
            short8 pa = *reinterpret_cast<const short8*>(
                (const char*)Pl + w * 2304 + lo * 144 + ks * 64 + hi * 16);
#pragma unroll
            for (int fd = 0; fd < 8; ++fd) {
                short8 bv = *reinterpret_cast<const short8*>(
                    (const char*)Vl + (fd * 16 + lo) * 144 + ks * 64 + hi * 16);
                oacc[fd] = __builtin_amdgcn_mfma_f32_16x16x32_bf16(pa, bv, oacc[fd], 0, 0, 0);
            }
        }
    }

    // ---- normalize + store bf16 ----
#pragma unroll
    for (int r = 0; r < 4; ++r) {
        const float inv = 1.0f / l_run[r];
        const size_t rowbase = (size_t)(b * S_ + q0 + w * 16 + hi * 4 + r) * H_ + headoff;
#pragma unroll
        for (int fd = 0; fd < 8; ++fd)
            O[rowbase + fd * 16 + lo] = f2bf(oacc[fd][r] * inv);
    }
}

// ---------------------------------------------------------------------------
// Launch
// ---------------------------------------------------------------------------
extern "C" void kernel_launch(void* const* d_in, const int* in_sizes, int n_in,
                              void* d_out, int out_size, void* d_ws, size_t ws_size,
                              hipStream_t stream)
{
    const float* hs       = (const float*)d_in[0];
    const float* Wq_down  = (const float*)d_in[1];
    const float* bq_down  = (const float*)d_in[2];
    const float* Wkv_down = (const float*)d_in[3];
    const float* bkv_down = (const float*)d_in[4];
    const float* Wq_up    = (const float*)d_in[5];
    const float* bq_up    = (const float*)d_in[6];
    const float* Wk_nope  = (const float*)d_in[7];
    const float* bk_nope  = (const float*)d_in[8];
    const float* Wk_rope  = (const float*)d_in[9];
    const float* bk_rope  = (const float*)d_in[10];
    const float* Wv_up    = (const float*)d_in[11];
    const float* bv_up    = (const float*)d_in[12];
    const float* Wo       = (const float*)d_in[13];
    const float* bo       = (const float*)d_in[14];
    float* out = (float*)d_out;

    // Workspace layout in ushort (bf16) units. Total 136.3 MB.
    ushort* ws = (ushort*)d_ws;
    ushort* hs_bf   = ws;                                // 8,388,608
    ushort* wqd_bf  = hs_bf  + (size_t)8388608;          // 1,048,576
    ushort* wkvd_bf = wqd_bf + (size_t)1048576;          // 1,048,576
    ushort* wqu_bf  = wkvd_bf+ (size_t)1048576;          // 1,048,576
    ushort* wkn_bf  = wqu_bf + (size_t)1048576;          //   524,288
    ushort* wkr_bf  = wkn_bf + (size_t)524288;           //   524,288
    ushort* wvu_bf  = wkr_bf + (size_t)524288;           // 1,048,576
    ushort* wo_bf   = wvu_bf + (size_t)1048576;          // 4,194,304
    ushort* lat_q   = wo_bf  + (size_t)4194304;          // 2,097,152
    ushort* lat_kv  = lat_q  + (size_t)2097152;          // 2,097,152
    ushort* qb      = lat_kv + (size_t)2097152;          // 8,388,608
    ushort* kb      = qb     + (size_t)8388608;          // 8,388,608
    ushort* krp     = kb     + (size_t)8388608;          // 4,194,304
    ushort* vb      = krp    + (size_t)4194304;          // 8,388,608
    ushort* vt      = vb     + (size_t)8388608;          // 8,388,608
    ushort* ob      = vt     + (size_t)8388608;          // 8,388,608

    const int M = B_ * S_;   // 4096

    // ---- casts ----
    cast_bf<<<8192, 256, 0, stream>>>(hs, hs_bf, 8388608);
    cast_bf<<<1024, 256, 0, stream>>>(Wq_down, wqd_bf, 1048576);
    cast_bf<<<1024, 256, 0, stream>>>(Wkv_down, wkvd_bf, 1048576);
    cast_bf<<<1024, 256, 0, stream>>>(Wq_up, wqu_bf, 1048576);
    cast_bf<<<512, 256, 0, stream>>>(Wk_nope, wkn_bf, 524288);
    cast_bf<<<512, 256, 0, stream>>>(Wk_rope, wkr_bf, 524288);
    cast_bf<<<1024, 256, 0, stream>>>(Wv_up, wvu_bf, 1048576);
    cast_bf<<<4096, 256, 0, stream>>>(Wo, wo_bf, 4194304);

    // ---- down projections (N=512, K=2048) ----
    gemm_mfma<1><<<dim3(4, 32), 256, 0, stream>>>(hs_bf, wqd_bf, bq_down, lat_q, M, 512, 2048, 512, 0);
    gemm_mfma<1><<<dim3(4, 32), 256, 0, stream>>>(hs_bf, wkvd_bf, bkv_down, lat_kv, M, 512, 2048, 512, 0);

    // ---- up projections (K=512) ----
    gemm_mfma<1><<<dim3(16, 32), 256, 0, stream>>>(lat_q, wqu_bf, bq_up, qb, M, 2048, 512, 2048, 0);
    gemm_mfma<1><<<dim3(8, 32), 256, 0, stream>>>(lat_kv, wkn_bf, bk_nope, kb, M, 1024, 512, 2048, 0);
    gemm_mfma<1><<<dim3(8, 32), 256, 0, stream>>>(lat_kv, wkr_bf, bk_rope, krp, M, 1024, 512, 1024, 0);
    gemm_mfma<1><<<dim3(16, 32), 256, 0, stream>>>(lat_kv, wvu_bf, bv_up, vb, M, 2048, 512, 2048, 0);

    // ---- rope into kb[:,1024:2048) ----
    rope_bf<<<dim3(M, 2), 256, 0, stream>>>(krp, kb);

    // ---- V transpose ----
    transpose_v<<<dim3(32, 32), 256, 0, stream>>>(vb, vt);

    // ---- attention ----
    attn_mfma<<<dim3(S_ / 64, B_ * NH_), 256, 0, stream>>>(qb, kb, vt, ob);

    // ---- output projection (fp32 out) ----
    gemm_mfma<0><<<dim3(16, 32), 256, 0, stream>>>(ob, wo_bf, bo, out, M, 2048, 2048, 2048, 0);
}

// Round 4
// 562.454 us; speedup vs baseline: 5.6806x; 1.1899x over previous
//
#include <hip/hip_runtime.h>
#include <math.h>

#define B_  2
#define S_  2048
#define H_  2048
#define NH_ 16
#define HD_ 128

typedef __attribute__((ext_vector_type(8))) short short8;
typedef __attribute__((ext_vector_type(4))) float f32x4;

#define AS1 __attribute__((address_space(1)))
#define AS3 __attribute__((address_space(3)))

__device__ __forceinline__ ushort f2bf(float f) {
    union { float f; unsigned u; } x; x.f = f;
    unsigned r = (x.u + 0x7FFF + ((x.u >> 16) & 1)) >> 16;
    return (ushort)r;
}
__device__ __forceinline__ float bf2f(ushort u) {
    union { unsigned u; float f; } x; x.u = ((unsigned)u) << 16;
    return x.f;
}
__device__ __forceinline__ void gload_lds16(const void* g, void* l) {
    __builtin_amdgcn_global_load_lds((const AS1 void*)g, (AS3 void*)l, 16, 0, 0);
}

// ---------------------------------------------------------------------------
// Fused fp32 -> bf16 cast over 8 segments (1 launch instead of 8)
// ---------------------------------------------------------------------------
struct CastSeg { const float* src; ushort* dst; unsigned n4; };
struct CastParams { CastSeg seg[8]; unsigned total4; };

__global__ __launch_bounds__(256)
void cast_all(CastParams p)
{
    unsigned i = blockIdx.x * 256 + threadIdx.x;   // float4 index
    if (i >= p.total4) return;
#pragma unroll
    for (int s = 0; s < 8; ++s) {
        if (i < p.seg[s].n4) {
            const float4 v = reinterpret_cast<const float4*>(p.seg[s].src)[i];
            ushort4 o;
            o.x = f2bf(v.x); o.y = f2bf(v.y); o.z = f2bf(v.z); o.w = f2bf(v.w);
            reinterpret_cast<ushort4*>(p.seg[s].dst)[i] = o;
            return;
        }
        i -= p.seg[s].n4;
    }
}

// ---------------------------------------------------------------------------
// bf16 MFMA GEMM: C[m, c0+n] = sum_k A[m,k]*W[n,k] + bias[n]
// BM=128 fixed, BN in {64,128}. 4 waves arranged WM x WN.
// OUT_MODE: 0 = f32 C; 1 = bf16 C; 2 = bf16 (v*scale) C (for Q);
//           3 = bf16 V-transposed C -> vt[bh][d][token]
// ---------------------------------------------------------------------------
template<int OUT_MODE, int BN, int WM, int WN>
__global__ __launch_bounds__(256)
void gemm_mfma(const ushort* __restrict__ A, const ushort* __restrict__ W,
               const float* __restrict__ bias, void* __restrict__ Cv,
               int M, int N, int K, int ldc, int c0)
{
    constexpr int FM = 128 / (WM * 16);
    constexpr int FN = BN / (WN * 16);
    __shared__ ushort Asm[128 * 32];
    __shared__ ushort Bsm[BN * 32];

    const int tid  = threadIdx.x;
    const int w    = tid >> 6;
    const int lane = tid & 63;
    const int lo   = lane & 15;
    const int hi   = lane >> 4;
    const int wm   = (WN == 1) ? w : (w / WN);
    const int wn   = (WN == 1) ? 0 : (w % WN);
    const int m0   = blockIdx.y * 128;
    const int n0   = blockIdx.x * BN;
    const int l4   = lane >> 2;
    const int s4   = lane & 3;

    f32x4 acc[FM][FN];
#pragma unroll
    for (int i = 0; i < FM; ++i)
#pragma unroll
        for (int j = 0; j < FN; ++j) acc[i][j] = f32x4{0.f, 0.f, 0.f, 0.f};

    for (int k0 = 0; k0 < K; k0 += 32) {
        __syncthreads();
#pragma unroll
        for (int t = 0; t < 2; ++t) {
            const int row = w * 32 + t * 16 + l4;
            gload_lds16(A + (size_t)(m0 + row) * K + k0 + s4 * 8,
                        (char*)Asm + w * 2048 + t * 1024);
        }
        if constexpr (BN == 128) {
#pragma unroll
            for (int t = 0; t < 2; ++t) {
                const int row = w * 32 + t * 16 + l4;
                gload_lds16(W + (size_t)(n0 + row) * K + k0 + s4 * 8,
                            (char*)Bsm + w * 2048 + t * 1024);
            }
        } else {
            const int row = w * 16 + l4;
            gload_lds16(W + (size_t)(n0 + row) * K + k0 + s4 * 8,
                        (char*)Bsm + w * 1024);
        }
        __syncthreads();

        short8 a[FM], b[FN];
#pragma unroll
        for (int i = 0; i < FM; ++i)
            a[i] = *reinterpret_cast<const short8*>(
                &Asm[(wm * (128 / WM) + i * 16 + lo) * 32 + hi * 8]);
#pragma unroll
        for (int j = 0; j < FN; ++j)
            b[j] = *reinterpret_cast<const short8*>(
                &Bsm[(wn * (BN / WN) + j * 16 + lo) * 32 + hi * 8]);
#pragma unroll
        for (int i = 0; i < FM; ++i)
#pragma unroll
            for (int j = 0; j < FN; ++j)
                acc[i][j] = __builtin_amdgcn_mfma_f32_16x16x32_bf16(a[i], b[j], acc[i][j], 0, 0, 0);
    }

    // epilogue
#pragma unroll
    for (int j = 0; j < FN; ++j) {
        const int col = n0 + wn * (BN / WN) + j * 16 + lo;
        const float bv = bias[col];
#pragma unroll
        for (int i = 0; i < FM; ++i) {
            const int row0 = m0 + wm * (128 / WM) + i * 16 + hi * 4;
            if constexpr (OUT_MODE == 3) {
                const int bb = row0 >> 11, sidx = row0 & 2047;
                const int hh = col >> 7, dd = col & 127;
                ushort4 o;
                o.x = f2bf(acc[i][j][0] + bv);
                o.y = f2bf(acc[i][j][1] + bv);
                o.z = f2bf(acc[i][j][2] + bv);
                o.w = f2bf(acc[i][j][3] + bv);
                *reinterpret_cast<ushort4*>(
                    (ushort*)Cv + (((size_t)(bb * 16 + hh) * 128 + dd) << 11) + sidx) = o;
            } else {
#pragma unroll
                for (int r = 0; r < 4; ++r) {
                    float v = acc[i][j][r] + bv;
                    if constexpr (OUT_MODE == 2) v *= 0.08838834764831845f;
                    const size_t idx = (size_t)(row0 + r) * ldc + c0 + col;
                    if constexpr (OUT_MODE == 0) ((float*)Cv)[idx] = v;
                    else                         ((ushort*)Cv)[idx] = f2bf(v);
                }
            }
        }
    }
}

// ---------------------------------------------------------------------------
// RoPE: read pre-rotary k_rope (bf16, [4096][1024]), write rotated bf16 into
// kb cols [1024,2048). grid (4096, 2) x 256.
// ---------------------------------------------------------------------------
__global__ void rope_bf(const ushort* __restrict__ pre, ushort* __restrict__ kb)
{
    const int row = blockIdx.x;
    const int d   = blockIdx.y * 256 + threadIdx.x;   // 0..511
    const int pos = row & (S_ - 1);
    const float inv = expf((float)d * -0.017988946f); // ln(10000)/512
    const float ang = (float)pos * inv;
    const float c = cosf(ang), s = sinf(ang);
    const float x1 = bf2f(pre[(size_t)row * 1024 + d]);
    const float x2 = bf2f(pre[(size_t)row * 1024 + 512 + d]);
    kb[(size_t)row * 2048 + 1024 + d]       = f2bf(x1 * c - x2 * s);
    kb[(size_t)row * 2048 + 1024 + 512 + d] = f2bf(x1 * s + x2 * c);
}

// ---------------------------------------------------------------------------
// Flash attention, bf16 MFMA. Block = 128 q-rows for one (b,h); 4 waves,
// each wave 32 q-rows (2 fragments). KV tile = 64 keys.
// K LDS XOR-swizzled (256B rows); Vt/P LDS padded to 72 bf16/row.
// Async stage split: next tile's global loads issued before compute,
// LDS writes after the post-compute barrier (T14). setprio on MFMA (T5).
// Scale (1/sqrt(128)) is pre-folded into Q by the q-GEMM epilogue.
// ---------------------------------------------------------------------------
__global__ __launch_bounds__(256)
void attn_mfma(const ushort* __restrict__ Q, const ushort* __restrict__ K,
               const ushort* __restrict__ Vt, ushort* __restrict__ O)
{
    __shared__ ushort Kl[64 * 128];     // 16 KB, swizzled
    __shared__ ushort Vl[128 * 72];     // 18 KB, [d][k] padded
    __shared__ ushort Pl[4 * 32 * 72];  // 18 KB, per-wave 32 rows

    const int tid  = threadIdx.x;
    const int w    = tid >> 6;
    const int lane = tid & 63;
    const int lo   = lane & 15;
    const int hi   = lane >> 4;
    const int bh   = blockIdx.y;
    const int b    = bh >> 4;
    const int q0   = blockIdx.x * 128;
    const size_t headoff = (size_t)(bh & 15) * HD_;

    // Q fragments (pre-scaled): 2 frags x 4 k-slices
    short8 aq[2][4];
#pragma unroll
    for (int i = 0; i < 2; ++i) {
        const ushort* qrow = Q + (size_t)(b * S_ + q0 + w * 32 + i * 16 + lo) * H_ + headoff;
#pragma unroll
        for (int kd = 0; kd < 4; ++kd)
            aq[i][kd] = *reinterpret_cast<const short8*>(qrow + kd * 32 + hi * 8);
    }

    f32x4 oacc[2][8];
#pragma unroll
    for (int i = 0; i < 2; ++i)
#pragma unroll
        for (int fd = 0; fd < 8; ++fd) oacc[i][fd] = f32x4{0.f, 0.f, 0.f, 0.f};
    float m_run[2][4], l_run[2][4];
#pragma unroll
    for (int i = 0; i < 2; ++i)
#pragma unroll
        for (int r = 0; r < 4; ++r) { m_run[i][r] = -INFINITY; l_run[i][r] = 0.f; }

    const ushort* kbase = K  + (size_t)(b * S_) * H_ + headoff;
    const ushort* vbase = Vt + (size_t)bh * 128 * S_;

    short8 kst[4], vst[4];
    auto issue_loads = [&](int kt) {
#pragma unroll
        for (int r = 0; r < 4; ++r) {
            const int c = r * 256 + tid;
            kst[r] = *reinterpret_cast<const short8*>(
                kbase + (size_t)(kt * 64 + (c >> 4)) * H_ + (c & 15) * 8);
            vst[r] = *reinterpret_cast<const short8*>(
                vbase + (size_t)(c >> 3) * S_ + kt * 64 + (c & 7) * 8);
        }
    };
    auto write_lds = [&]() {
#pragma unroll
        for (int r = 0; r < 4; ++r) {
            const int c = r * 256 + tid;
            const int key = c >> 4, slot = c & 15;
            *reinterpret_cast<short8*>(
                (char*)Kl + key * 256 + ((slot * 16) ^ ((key & 7) << 4))) = kst[r];
            *reinterpret_cast<short8*>(
                (char*)Vl + (c >> 3) * 144 + (c & 7) * 16) = vst[r];
        }
    };

    issue_loads(0);
    write_lds();
    __syncthreads();

    const int swz = (lo & 7) << 4;

    for (int kt = 0; kt < S_ / 64; ++kt) {
        if (kt + 1 < S_ / 64) issue_loads(kt + 1);   // in flight across compute

        // ---- S = Q K^T  (32q x 64k per wave) ----
        f32x4 s[2][4];
#pragma unroll
        for (int i = 0; i < 2; ++i)
#pragma unroll
            for (int fn = 0; fn < 4; ++fn) s[i][fn] = f32x4{0.f, 0.f, 0.f, 0.f};

        __builtin_amdgcn_s_setprio(1);
#pragma unroll
        for (int fn = 0; fn < 4; ++fn) {
            const int kbyte = (fn * 16 + lo) * 256;
#pragma unroll
            for (int kd = 0; kd < 4; ++kd) {
                short8 bk = *reinterpret_cast<const short8*>(
                    (const char*)Kl + kbyte + ((kd * 64 + hi * 16) ^ swz));
#pragma unroll
                for (int i = 0; i < 2; ++i)
                    s[i][fn] = __builtin_amdgcn_mfma_f32_16x16x32_bf16(aq[i][kd], bk, s[i][fn], 0, 0, 0);
            }
        }
        __builtin_amdgcn_s_setprio(0);

        // ---- online softmax (8 rows per wave-thread-group) ----
        float f_r[2][4];
#pragma unroll
        for (int i = 0; i < 2; ++i) {
#pragma unroll
            for (int r = 0; r < 4; ++r) {
                const float s0 = s[i][0][r], s1 = s[i][1][r],
                            s2 = s[i][2][r], s3 = s[i][3][r];
                float mx = fmaxf(fmaxf(s0, s1), fmaxf(s2, s3));
                mx = fmaxf(mx, __shfl_xor(mx, 1));
                mx = fmaxf(mx, __shfl_xor(mx, 2));
                mx = fmaxf(mx, __shfl_xor(mx, 4));
                mx = fmaxf(mx, __shfl_xor(mx, 8));
                const float mnew = fmaxf(m_run[i][r], mx);
                const float f = __expf(m_run[i][r] - mnew);
                m_run[i][r] = mnew;
                const float p0 = __expf(s0 - mnew), p1 = __expf(s1 - mnew),
                            p2 = __expf(s2 - mnew), p3 = __expf(s3 - mnew);
                float ls = p0 + p1 + p2 + p3;
                ls += __shfl_xor(ls, 1);
                ls += __shfl_xor(ls, 2);
                ls += __shfl_xor(ls, 4);
                ls += __shfl_xor(ls, 8);
                l_run[i][r] = l_run[i][r] * f + ls;
                f_r[i][r] = f;
                ushort* prow = &Pl[(size_t)(w * 32 + i * 16 + hi * 4 + r) * 72 + lo];
                prow[0]  = f2bf(p0);
                prow[16] = f2bf(p1);
                prow[32] = f2bf(p2);
                prow[48] = f2bf(p3);
            }
        }

#pragma unroll
        for (int i = 0; i < 2; ++i)
#pragma unroll
            for (int fd = 0; fd < 8; ++fd)
#pragma unroll
                for (int r = 0; r < 4; ++r)
                    oacc[i][fd][r] *= f_r[i][r];

        // ---- O += P V ----
        __builtin_amdgcn_s_setprio(1);
#pragma unroll
        for (int ks = 0; ks < 2; ++ks) {
            short8 pa[2];
#pragma unroll
            for (int i = 0; i < 2; ++i)
                pa[i] = *reinterpret_cast<const short8*>(
                    (const char*)Pl + (w * 32 + i * 16 + lo) * 144 + ks * 64 + hi * 16);
#pragma unroll
            for (int fd = 0; fd < 8; ++fd) {
                short8 bv = *reinterpret_cast<const short8*>(
                    (const char*)Vl + (fd * 16 + lo) * 144 + ks * 64 + hi * 16);
#pragma unroll
                for (int i = 0; i < 2; ++i)
                    oacc[i][fd] = __builtin_amdgcn_mfma_f32_16x16x32_bf16(pa[i], bv, oacc[i][fd], 0, 0, 0);
            }
        }
        __builtin_amdgcn_s_setprio(0);

        __syncthreads();                 // all waves done reading Kl/Vl
        if (kt + 1 < S_ / 64) {
            write_lds();                 // compiler inserts vmcnt wait here
            __syncthreads();
        }
    }

    // ---- normalize + store bf16 ----
#pragma unroll
    for (int i = 0; i < 2; ++i)
#pragma unroll
        for (int r = 0; r < 4; ++r) {
            const float inv = 1.0f / l_run[i][r];
            ushort* orow = O + (size_t)(b * S_ + q0 + w * 32 + i * 16 + hi * 4 + r) * H_
                             + headoff + lo;
#pragma unroll
            for (int fd = 0; fd < 8; ++fd)
                orow[fd * 16] = f2bf(oacc[i][fd][r] * inv);
        }
}

// ---------------------------------------------------------------------------
// Launch
// ---------------------------------------------------------------------------
extern "C" void kernel_launch(void* const* d_in, const int* in_sizes, int n_in,
                              void* d_out, int out_size, void* d_ws, size_t ws_size,
                              hipStream_t stream)
{
    const float* hs       = (const float*)d_in[0];
    const float* Wq_down  = (const float*)d_in[1];
    const float* bq_down  = (const float*)d_in[2];
    const float* Wkv_down = (const float*)d_in[3];
    const float* bkv_down = (const float*)d_in[4];
    const float* Wq_up    = (const float*)d_in[5];
    const float* bq_up    = (const float*)d_in[6];
    const float* Wk_nope  = (const float*)d_in[7];
    const float* bk_nope  = (const float*)d_in[8];
    const float* Wk_rope  = (const float*)d_in[9];
    const float* bk_rope  = (const float*)d_in[10];
    const float* Wv_up    = (const float*)d_in[11];
    const float* bv_up    = (const float*)d_in[12];
    const float* Wo       = (const float*)d_in[13];
    const float* bo       = (const float*)d_in[14];
    float* out = (float*)d_out;

    // Workspace layout in ushort (bf16) units. Total ~120 MB.
    ushort* ws = (ushort*)d_ws;
    ushort* hs_bf   = ws;                                // 8,388,608
    ushort* wqd_bf  = hs_bf  + (size_t)8388608;          // 1,048,576
    ushort* wkvd_bf = wqd_bf + (size_t)1048576;          // 1,048,576
    ushort* wqu_bf  = wkvd_bf+ (size_t)1048576;          // 1,048,576
    ushort* wkn_bf  = wqu_bf + (size_t)1048576;          //   524,288
    ushort* wkr_bf  = wkn_bf + (size_t)524288;           //   524,288
    ushort* wvu_bf  = wkr_bf + (size_t)524288;           // 1,048,576
    ushort* wo_bf   = wvu_bf + (size_t)1048576;          // 4,194,304
    ushort* lat_q   = wo_bf  + (size_t)4194304;          // 2,097,152
    ushort* lat_kv  = lat_q  + (size_t)2097152;          // 2,097,152
    ushort* qb      = lat_kv + (size_t)2097152;          // 8,388,608
    ushort* kb      = qb     + (size_t)8388608;          // 8,388,608
    ushort* krp     = kb     + (size_t)8388608;          // 4,194,304
    ushort* vt      = krp    + (size_t)4194304;          // 8,388,608
    ushort* ob      = vt     + (size_t)8388608;          // 8,388,608

    const int M = B_ * S_;   // 4096

    // ---- fused casts (1 launch) ----
    CastParams cp;
    cp.seg[0] = { hs,       hs_bf,   8388608u / 4 };
    cp.seg[1] = { Wq_down,  wqd_bf,  1048576u / 4 };
    cp.seg[2] = { Wkv_down, wkvd_bf, 1048576u / 4 };
    cp.seg[3] = { Wq_up,    wqu_bf,  1048576u / 4 };
    cp.seg[4] = { Wk_nope,  wkn_bf,   524288u / 4 };
    cp.seg[5] = { Wk_rope,  wkr_bf,   524288u / 4 };
    cp.seg[6] = { Wv_up,    wvu_bf,  1048576u / 4 };
    cp.seg[7] = { Wo,       wo_bf,   4194304u / 4 };
    cp.total4 = (8388608u + 1048576u * 4 + 524288u * 2 + 4194304u) / 4;
    cast_all<<<(cp.total4 + 255) / 256, 256, 0, stream>>>(cp);

    // ---- down projections (N=512, K=2048): 128x64 tiles, 256 blocks ----
    gemm_mfma<1, 64, 4, 1><<<dim3(8, 32), 256, 0, stream>>>(
        hs_bf, wqd_bf, bq_down, lat_q, M, 512, 2048, 512, 0);
    gemm_mfma<1, 64, 4, 1><<<dim3(8, 32), 256, 0, stream>>>(
        hs_bf, wkvd_bf, bkv_down, lat_kv, M, 512, 2048, 512, 0);

    // ---- up projections (K=512) ----
    gemm_mfma<2, 128, 2, 2><<<dim3(16, 32), 256, 0, stream>>>(   // q, pre-scaled
        lat_q, wqu_bf, bq_up, qb, M, 2048, 512, 2048, 0);
    gemm_mfma<1, 128, 2, 2><<<dim3(8, 32), 256, 0, stream>>>(
        lat_kv, wkn_bf, bk_nope, kb, M, 1024, 512, 2048, 0);
    gemm_mfma<1, 128, 2, 2><<<dim3(8, 32), 256, 0, stream>>>(
        lat_kv, wkr_bf, bk_rope, krp, M, 1024, 512, 1024, 0);
    gemm_mfma<3, 128, 2, 2><<<dim3(16, 32), 256, 0, stream>>>(   // v, direct vt
        lat_kv, wvu_bf, bv_up, vt, M, 2048, 512, 2048, 0);

    // ---- rope into kb[:,1024:2048) ----
    rope_bf<<<dim3(M, 2), 256, 0, stream>>>(krp, kb);

    // ---- attention ----
    attn_mfma<<<dim3(S_ / 128, B_ * NH_), 256, 0, stream>>>(qb, kb, vt, ob);

    // ---- output projection (fp32 out) ----
    gemm_mfma<0, 128, 2, 2><<<dim3(16, 32), 256, 0, stream>>>(
        ob, wo_bf, bo, out, M, 2048, 2048, 2048, 0);
}

// Round 5
// 473.382 us; speedup vs baseline: 6.7495x; 1.1882x over previous
//
#include <hip/hip_runtime.h>
#include <math.h>

#define B_  2
#define S_  2048
#define H_  2048
#define NH_ 16
#define HD_ 128

typedef __attribute__((ext_vector_type(8))) short short8;
typedef __attribute__((ext_vector_type(4))) float f32x4;

#define AS1 __attribute__((address_space(1)))
#define AS3 __attribute__((address_space(3)))

__device__ __forceinline__ ushort f2bf(float f) {
    union { float f; unsigned u; } x; x.f = f;
    unsigned r = (x.u + 0x7FFF + ((x.u >> 16) & 1)) >> 16;
    return (ushort)r;
}
__device__ __forceinline__ float bf2f(ushort u) {
    union { unsigned u; float f; } x; x.u = ((unsigned)u) << 16;
    return x.f;
}
__device__ __forceinline__ void gload_lds16(const void* g, void* l) {
    __builtin_amdgcn_global_load_lds((const AS1 void*)g, (AS3 void*)l, 16, 0, 0);
}

// ---------------------------------------------------------------------------
// Fused fp32 -> bf16 cast over 8 segments (1 launch instead of 8)
// ---------------------------------------------------------------------------
struct CastSeg { const float* src; ushort* dst; unsigned n4; };
struct CastParams { CastSeg seg[8]; unsigned total4; };

__global__ __launch_bounds__(256)
void cast_all(CastParams p)
{
    unsigned i = blockIdx.x * 256 + threadIdx.x;   // float4 index
    if (i >= p.total4) return;
#pragma unroll
    for (int s = 0; s < 8; ++s) {
        if (i < p.seg[s].n4) {
            const float4 v = reinterpret_cast<const float4*>(p.seg[s].src)[i];
            ushort4 o;
            o.x = f2bf(v.x); o.y = f2bf(v.y); o.z = f2bf(v.z); o.w = f2bf(v.w);
            reinterpret_cast<ushort4*>(p.seg[s].dst)[i] = o;
            return;
        }
        i -= p.seg[s].n4;
    }
}

// ---------------------------------------------------------------------------
// bf16 MFMA GEMM: C[m, c0+n] = sum_k A[m,k]*W[n,k] + bias[n]
// BM=128 fixed, BN in {64,128}. 4 waves arranged WM x WN.
// OUT_MODE: 0 = f32 C; 1 = bf16 C; 2 = bf16 (v*scale) C (for Q);
//           3 = bf16 V-transposed C -> vt[bh][d][token]
// ---------------------------------------------------------------------------
template<int OUT_MODE, int BN, int WM, int WN>
__global__ __launch_bounds__(256)
void gemm_mfma(const ushort* __restrict__ A, const ushort* __restrict__ W,
               const float* __restrict__ bias, void* __restrict__ Cv,
               int M, int N, int K, int ldc, int c0)
{
    constexpr int FM = 128 / (WM * 16);
    constexpr int FN = BN / (WN * 16);
    __shared__ ushort Asm[128 * 32];
    __shared__ ushort Bsm[BN * 32];

    const int tid  = threadIdx.x;
    const int w    = tid >> 6;
    const int lane = tid & 63;
    const int lo   = lane & 15;
    const int hi   = lane >> 4;
    const int wm   = (WN == 1) ? w : (w / WN);
    const int wn   = (WN == 1) ? 0 : (w % WN);
    const int m0   = blockIdx.y * 128;
    const int n0   = blockIdx.x * BN;
    const int l4   = lane >> 2;
    const int s4   = lane & 3;

    f32x4 acc[FM][FN];
#pragma unroll
    for (int i = 0; i < FM; ++i)
#pragma unroll
        for (int j = 0; j < FN; ++j) acc[i][j] = f32x4{0.f, 0.f, 0.f, 0.f};

    for (int k0 = 0; k0 < K; k0 += 32) {
        __syncthreads();
#pragma unroll
        for (int t = 0; t < 2; ++t) {
            const int row = w * 32 + t * 16 + l4;
            gload_lds16(A + (size_t)(m0 + row) * K + k0 + s4 * 8,
                        (char*)Asm + w * 2048 + t * 1024);
        }
        if constexpr (BN == 128) {
#pragma unroll
            for (int t = 0; t < 2; ++t) {
                const int row = w * 32 + t * 16 + l4;
                gload_lds16(W + (size_t)(n0 + row) * K + k0 + s4 * 8,
                            (char*)Bsm + w * 2048 + t * 1024);
            }
        } else {
            const int row = w * 16 + l4;
            gload_lds16(W + (size_t)(n0 + row) * K + k0 + s4 * 8,
                        (char*)Bsm + w * 1024);
        }
        __syncthreads();

        short8 a[FM], b[FN];
#pragma unroll
        for (int i = 0; i < FM; ++i)
            a[i] = *reinterpret_cast<const short8*>(
                &Asm[(wm * (128 / WM) + i * 16 + lo) * 32 + hi * 8]);
#pragma unroll
        for (int j = 0; j < FN; ++j)
            b[j] = *reinterpret_cast<const short8*>(
                &Bsm[(wn * (BN / WN) + j * 16 + lo) * 32 + hi * 8]);
#pragma unroll
        for (int i = 0; i < FM; ++i)
#pragma unroll
            for (int j = 0; j < FN; ++j)
                acc[i][j] = __builtin_amdgcn_mfma_f32_16x16x32_bf16(a[i], b[j], acc[i][j], 0, 0, 0);
    }

    // epilogue
#pragma unroll
    for (int j = 0; j < FN; ++j) {
        const int col = n0 + wn * (BN / WN) + j * 16 + lo;
        const float bv = bias[col];
#pragma unroll
        for (int i = 0; i < FM; ++i) {
            const int row0 = m0 + wm * (128 / WM) + i * 16 + hi * 4;
            if constexpr (OUT_MODE == 3) {
                const int bb = row0 >> 11, sidx = row0 & 2047;
                const int hh = col >> 7, dd = col & 127;
                ushort4 o;
                o.x = f2bf(acc[i][j][0] + bv);
                o.y = f2bf(acc[i][j][1] + bv);
                o.z = f2bf(acc[i][j][2] + bv);
                o.w = f2bf(acc[i][j][3] + bv);
                *reinterpret_cast<ushort4*>(
                    (ushort*)Cv + (((size_t)(bb * 16 + hh) * 128 + dd) << 11) + sidx) = o;
            } else {
#pragma unroll
                for (int r = 0; r < 4; ++r) {
                    float v = acc[i][j][r] + bv;
                    if constexpr (OUT_MODE == 2) v *= 0.08838834764831845f;
                    const size_t idx = (size_t)(row0 + r) * ldc + c0 + col;
                    if constexpr (OUT_MODE == 0) ((float*)Cv)[idx] = v;
                    else                         ((ushort*)Cv)[idx] = f2bf(v);
                }
            }
        }
    }
}

// ---------------------------------------------------------------------------
// RoPE: read pre-rotary k_rope (bf16, [4096][1024]), write rotated bf16 into
// kb cols [1024,2048). grid (4096, 2) x 256.
// ---------------------------------------------------------------------------
__global__ void rope_bf(const ushort* __restrict__ pre, ushort* __restrict__ kb)
{
    const int row = blockIdx.x;
    const int d   = blockIdx.y * 256 + threadIdx.x;   // 0..511
    const int pos = row & (S_ - 1);
    const float inv = expf((float)d * -0.017988946f); // ln(10000)/512
    const float ang = (float)pos * inv;
    const float c = cosf(ang), s = sinf(ang);
    const float x1 = bf2f(pre[(size_t)row * 1024 + d]);
    const float x2 = bf2f(pre[(size_t)row * 1024 + 512 + d]);
    kb[(size_t)row * 2048 + 1024 + d]       = f2bf(x1 * c - x2 * s);
    kb[(size_t)row * 2048 + 1024 + 512 + d] = f2bf(x1 * s + x2 * c);
}

// ---------------------------------------------------------------------------
// Flash attention, bf16 MFMA. Block = 128 q-rows for one (b,h).
// 8 waves x 16 q-rows each (low register footprint -> 2+ blocks/CU).
// KV tile = 64 keys. K LDS XOR-swizzled (256B rows); Vt/P LDS padded to
// 72 bf16/row. T14 async stage split + T5 setprio. Scale pre-folded into Q.
// ---------------------------------------------------------------------------
__global__ __launch_bounds__(512)
void attn_mfma(const ushort* __restrict__ Q, const ushort* __restrict__ K,
               const ushort* __restrict__ Vt, ushort* __restrict__ O)
{
    __shared__ ushort Kl[64 * 128];     // 16 KB, swizzled
    __shared__ ushort Vl[128 * 72];     // 18 KB, [d][k] padded
    __shared__ ushort Pl[8 * 16 * 72];  // 18 KB, per-wave 16 rows

    const int tid  = threadIdx.x;
    const int w    = tid >> 6;          // 0..7
    const int lane = tid & 63;
    const int lo   = lane & 15;
    const int hi   = lane >> 4;
    const int bh   = blockIdx.y;
    const int b    = bh >> 4;
    const int q0   = blockIdx.x * 128;
    const size_t headoff = (size_t)(bh & 15) * HD_;

    // Q fragments (pre-scaled): wave w owns q-rows [w*16, w*16+16)
    short8 aq[4];
    {
        const ushort* qrow = Q + (size_t)(b * S_ + q0 + w * 16 + lo) * H_ + headoff;
#pragma unroll
        for (int kd = 0; kd < 4; ++kd)
            aq[kd] = *reinterpret_cast<const short8*>(qrow + kd * 32 + hi * 8);
    }

    f32x4 oacc[8];
#pragma unroll
    for (int fd = 0; fd < 8; ++fd) oacc[fd] = f32x4{0.f, 0.f, 0.f, 0.f};
    float m_run[4], l_run[4];
#pragma unroll
    for (int r = 0; r < 4; ++r) { m_run[r] = -INFINITY; l_run[r] = 0.f; }

    const ushort* kbase = K  + (size_t)(b * S_) * H_ + headoff;
    const ushort* vbase = Vt + (size_t)bh * 128 * S_;

    short8 kst[2], vst[2];
    auto issue_loads = [&](int kt) {
#pragma unroll
        for (int r = 0; r < 2; ++r) {
            const int c = r * 512 + tid;       // 0..1023 16B chunks
            kst[r] = *reinterpret_cast<const short8*>(
                kbase + (size_t)(kt * 64 + (c >> 4)) * H_ + (c & 15) * 8);
            vst[r] = *reinterpret_cast<const short8*>(
                vbase + (size_t)(c >> 3) * S_ + kt * 64 + (c & 7) * 8);
        }
    };
    auto write_lds = [&]() {
#pragma unroll
        for (int r = 0; r < 2; ++r) {
            const int c = r * 512 + tid;
            const int key = c >> 4, slot = c & 15;
            *reinterpret_cast<short8*>(
                (char*)Kl + key * 256 + ((slot * 16) ^ ((key & 7) << 4))) = kst[r];
            *reinterpret_cast<short8*>(
                (char*)Vl + (c >> 3) * 144 + (c & 7) * 16) = vst[r];
        }
    };

    issue_loads(0);
    write_lds();
    __syncthreads();

    const int swz = (lo & 7) << 4;

    for (int kt = 0; kt < S_ / 64; ++kt) {
        if (kt + 1 < S_ / 64) issue_loads(kt + 1);   // in flight across compute

        // ---- S = Q K^T  (16q x 64k per wave) ----
        f32x4 s[4];
#pragma unroll
        for (int fn = 0; fn < 4; ++fn) s[fn] = f32x4{0.f, 0.f, 0.f, 0.f};

        __builtin_amdgcn_s_setprio(1);
#pragma unroll
        for (int fn = 0; fn < 4; ++fn) {
            const int kbyte = (fn * 16 + lo) * 256;
#pragma unroll
            for (int kd = 0; kd < 4; ++kd) {
                short8 bk = *reinterpret_cast<const short8*>(
                    (const char*)Kl + kbyte + ((kd * 64 + hi * 16) ^ swz));
                s[fn] = __builtin_amdgcn_mfma_f32_16x16x32_bf16(aq[kd], bk, s[fn], 0, 0, 0);
            }
        }
        __builtin_amdgcn_s_setprio(0);

        // ---- online softmax (4 rows per thread-group) ----
        float f_r[4];
#pragma unroll
        for (int r = 0; r < 4; ++r) {
            const float s0 = s[0][r], s1 = s[1][r], s2 = s[2][r], s3 = s[3][r];
            float mx = fmaxf(fmaxf(s0, s1), fmaxf(s2, s3));
            mx = fmaxf(mx, __shfl_xor(mx, 1));
            mx = fmaxf(mx, __shfl_xor(mx, 2));
            mx = fmaxf(mx, __shfl_xor(mx, 4));
            mx = fmaxf(mx, __shfl_xor(mx, 8));
            const float mnew = fmaxf(m_run[r], mx);
            const float f = __expf(m_run[r] - mnew);
            m_run[r] = mnew;
            const float p0 = __expf(s0 - mnew), p1 = __expf(s1 - mnew),
                        p2 = __expf(s2 - mnew), p3 = __expf(s3 - mnew);
            float ls = p0 + p1 + p2 + p3;
            ls += __shfl_xor(ls, 1);
            ls += __shfl_xor(ls, 2);
            ls += __shfl_xor(ls, 4);
            ls += __shfl_xor(ls, 8);
            l_run[r] = l_run[r] * f + ls;
            f_r[r] = f;
            ushort* prow = &Pl[(size_t)(w * 16 + hi * 4 + r) * 72 + lo];
            prow[0]  = f2bf(p0);
            prow[16] = f2bf(p1);
            prow[32] = f2bf(p2);
            prow[48] = f2bf(p3);
        }

#pragma unroll
        for (int fd = 0; fd < 8; ++fd)
#pragma unroll
            for (int r = 0; r < 4; ++r)
                oacc[fd][r] *= f_r[r];

        // ---- O += P V ----
        __builtin_amdgcn_s_setprio(1);
#pragma unroll
        for (int ks = 0; ks < 2; ++ks) {
            short8 pa = *reinterpret_cast<const short8*>(
                (const char*)Pl + (w * 16 + lo) * 144 + ks * 64 + hi * 16);
#pragma unroll
            for (int fd = 0; fd < 8; ++fd) {
                short8 bv = *reinterpret_cast<const short8*>(
                    (const char*)Vl + (fd * 16 + lo) * 144 + ks * 64 + hi * 16);
                oacc[fd] = __builtin_amdgcn_mfma_f32_16x16x32_bf16(pa, bv, oacc[fd], 0, 0, 0);
            }
        }
        __builtin_amdgcn_s_setprio(0);

        __syncthreads();                 // all waves done reading Kl/Vl/Pl
        if (kt + 1 < S_ / 64) {
            write_lds();                 // vmcnt wait inserted by compiler
            __syncthreads();
        }
    }

    // ---- normalize + store bf16 ----
#pragma unroll
    for (int r = 0; r < 4; ++r) {
        const float inv = 1.0f / l_run[r];
        ushort* orow = O + (size_t)(b * S_ + q0 + w * 16 + hi * 4 + r) * H_
                         + headoff + lo;
#pragma unroll
        for (int fd = 0; fd < 8; ++fd)
            orow[fd * 16] = f2bf(oacc[fd][r] * inv);
    }
}

// ---------------------------------------------------------------------------
// Launch
// ---------------------------------------------------------------------------
extern "C" void kernel_launch(void* const* d_in, const int* in_sizes, int n_in,
                              void* d_out, int out_size, void* d_ws, size_t ws_size,
                              hipStream_t stream)
{
    const float* hs       = (const float*)d_in[0];
    const float* Wq_down  = (const float*)d_in[1];
    const float* bq_down  = (const float*)d_in[2];
    const float* Wkv_down = (const float*)d_in[3];
    const float* bkv_down = (const float*)d_in[4];
    const float* Wq_up    = (const float*)d_in[5];
    const float* bq_up    = (const float*)d_in[6];
    const float* Wk_nope  = (const float*)d_in[7];
    const float* bk_nope  = (const float*)d_in[8];
    const float* Wk_rope  = (const float*)d_in[9];
    const float* bk_rope  = (const float*)d_in[10];
    const float* Wv_up    = (const float*)d_in[11];
    const float* bv_up    = (const float*)d_in[12];
    const float* Wo       = (const float*)d_in[13];
    const float* bo       = (const float*)d_in[14];
    float* out = (float*)d_out;

    // Workspace layout in ushort (bf16) units. Total ~120 MB.
    ushort* ws = (ushort*)d_ws;
    ushort* hs_bf   = ws;                                // 8,388,608
    ushort* wqd_bf  = hs_bf  + (size_t)8388608;          // 1,048,576
    ushort* wkvd_bf = wqd_bf + (size_t)1048576;          // 1,048,576
    ushort* wqu_bf  = wkvd_bf+ (size_t)1048576;          // 1,048,576
    ushort* wkn_bf  = wqu_bf + (size_t)1048576;          //   524,288
    ushort* wkr_bf  = wkn_bf + (size_t)524288;           //   524,288
    ushort* wvu_bf  = wkr_bf + (size_t)524288;           // 1,048,576
    ushort* wo_bf   = wvu_bf + (size_t)1048576;          // 4,194,304
    ushort* lat_q   = wo_bf  + (size_t)4194304;          // 2,097,152
    ushort* lat_kv  = lat_q  + (size_t)2097152;          // 2,097,152
    ushort* qb      = lat_kv + (size_t)2097152;          // 8,388,608
    ushort* kb      = qb     + (size_t)8388608;          // 8,388,608
    ushort* krp     = kb     + (size_t)8388608;          // 4,194,304
    ushort* vt      = krp    + (size_t)4194304;          // 8,388,608
    ushort* ob      = vt     + (size_t)8388608;          // 8,388,608

    const int M = B_ * S_;   // 4096

    // ---- fused casts (1 launch) ----
    CastParams cp;
    cp.seg[0] = { hs,       hs_bf,   8388608u / 4 };
    cp.seg[1] = { Wq_down,  wqd_bf,  1048576u / 4 };
    cp.seg[2] = { Wkv_down, wkvd_bf, 1048576u / 4 };
    cp.seg[3] = { Wq_up,    wqu_bf,  1048576u / 4 };
    cp.seg[4] = { Wk_nope,  wkn_bf,   524288u / 4 };
    cp.seg[5] = { Wk_rope,  wkr_bf,   524288u / 4 };
    cp.seg[6] = { Wv_up,    wvu_bf,  1048576u / 4 };
    cp.seg[7] = { Wo,       wo_bf,   4194304u / 4 };
    cp.total4 = (8388608u + 1048576u * 4 + 524288u * 2 + 4194304u) / 4;
    cast_all<<<(cp.total4 + 255) / 256, 256, 0, stream>>>(cp);

    // ---- down projections (N=512, K=2048): 128x64 tiles, 256 blocks ----
    gemm_mfma<1, 64, 4, 1><<<dim3(8, 32), 256, 0, stream>>>(
        hs_bf, wqd_bf, bq_down, lat_q, M, 512, 2048, 512, 0);
    gemm_mfma<1, 64, 4, 1><<<dim3(8, 32), 256, 0, stream>>>(
        hs_bf, wkvd_bf, bkv_down, lat_kv, M, 512, 2048, 512, 0);

    // ---- up projections (K=512) ----
    gemm_mfma<2, 128, 2, 2><<<dim3(16, 32), 256, 0, stream>>>(   // q, pre-scaled
        lat_q, wqu_bf, bq_up, qb, M, 2048, 512, 2048, 0);
    gemm_mfma<1, 128, 2, 2><<<dim3(8, 32), 256, 0, stream>>>(
        lat_kv, wkn_bf, bk_nope, kb, M, 1024, 512, 2048, 0);
    gemm_mfma<1, 128, 2, 2><<<dim3(8, 32), 256, 0, stream>>>(
        lat_kv, wkr_bf, bk_rope, krp, M, 1024, 512, 1024, 0);
    gemm_mfma<3, 128, 2, 2><<<dim3(16, 32), 256, 0, stream>>>(   // v, direct vt
        lat_kv, wvu_bf, bv_up, vt, M, 2048, 512, 2048, 0);

    // ---- rope into kb[:,1024:2048) ----
    rope_bf<<<dim3(M, 2), 256, 0, stream>>>(krp, kb);

    // ---- attention: 512 threads, 8 waves x 16 q-rows ----
    attn_mfma<<<dim3(S_ / 128, B_ * NH_), 512, 0, stream>>>(qb, kb, vt, ob);

    // ---- output projection (fp32 out) ----
    gemm_mfma<0, 128, 2, 2><<<dim3(16, 32), 256, 0, stream>>>(
        ob, wo_bf, bo, out, M, 2048, 2048, 2048, 0);
}

// Round 6
// 410.719 us; speedup vs baseline: 7.7793x; 1.1526x over previous
//
#include <hip/hip_runtime.h>
#include <math.h>

#define B_  2
#define S_  2048
#define H_  2048
#define NH_ 16
#define HD_ 128

typedef __attribute__((ext_vector_type(8))) short short8;
typedef __attribute__((ext_vector_type(4))) float f32x4;

#define AS1 __attribute__((address_space(1)))
#define AS3 __attribute__((address_space(3)))

// 1/sqrt(128) * log2(e)  (softmax runs in exp2 domain)
#define QSCALE_LOG2 (0.08838834764831845f * 1.4426950408889634f)

__device__ __forceinline__ ushort f2bf(float f) {
    union { float f; unsigned u; } x; x.f = f;
    unsigned r = (x.u + 0x7FFF + ((x.u >> 16) & 1)) >> 16;
    return (ushort)r;
}
__device__ __forceinline__ float bf2f(ushort u) {
    union { unsigned u; float f; } x; x.u = ((unsigned)u) << 16;
    return x.f;
}
__device__ __forceinline__ void gload_lds16(const void* g, void* l) {
    __builtin_amdgcn_global_load_lds((const AS1 void*)g, (AS3 void*)l, 16, 0, 0);
}

// ---------------------------------------------------------------------------
// Fused fp32 -> bf16 cast over 8 segments
// ---------------------------------------------------------------------------
struct CastSeg { const float* src; ushort* dst; unsigned n4; };
struct CastParams { CastSeg seg[8]; unsigned total4; };

__global__ __launch_bounds__(256)
void cast_all(CastParams p)
{
    unsigned i = blockIdx.x * 256 + threadIdx.x;   // float4 index
    if (i >= p.total4) return;
#pragma unroll
    for (int s = 0; s < 8; ++s) {
        if (i < p.seg[s].n4) {
            const float4 v = reinterpret_cast<const float4*>(p.seg[s].src)[i];
            ushort4 o;
            o.x = f2bf(v.x); o.y = f2bf(v.y); o.z = f2bf(v.z); o.w = f2bf(v.w);
            reinterpret_cast<ushort4*>(p.seg[s].dst)[i] = o;
            return;
        }
        i -= p.seg[s].n4;
    }
}

// ---------------------------------------------------------------------------
// Merged DOWN projection: C = hs @ W^T + b for both latents in one dispatch.
// N = 1024 total: cols [0,512) -> lat_q (Wq_down), [512,1024) -> lat_kv.
// BM=128, BN=64, K=2048, 4 waves stacked along M (WM=4), FM=2, FN=4.
// Grid (16, 32) = 512 blocks.
// ---------------------------------------------------------------------------
__global__ __launch_bounds__(256)
void gemm_down(const ushort* __restrict__ hs,
               const ushort* __restrict__ wqd, const ushort* __restrict__ wkvd,
               const float* __restrict__ bqd, const float* __restrict__ bkvd,
               ushort* __restrict__ latq, ushort* __restrict__ latkv)
{
    constexpr int K = 2048;
    __shared__ ushort Asm[128 * 32];
    __shared__ ushort Bsm[64 * 32];

    const int tid  = threadIdx.x;
    const int w    = tid >> 6;
    const int lane = tid & 63;
    const int lo   = lane & 15;
    const int hi   = lane >> 4;
    const int m0   = blockIdx.y * 128;
    const int n0   = blockIdx.x * 64;
    const int l4   = lane >> 2;
    const int s4   = lane & 3;

    const int seg = n0 >> 9;               // 0 = q latent, 1 = kv latent
    const int nl  = n0 & 511;
    const ushort* W    = (seg ? wkvd : wqd) + (size_t)nl * K;
    const float*  bias = (seg ? bkvd : bqd) + nl;
    ushort*       outp = seg ? latkv : latq;

    f32x4 acc[2][4];
#pragma unroll
    for (int i = 0; i < 2; ++i)
#pragma unroll
        for (int j = 0; j < 4; ++j) acc[i][j] = f32x4{0.f, 0.f, 0.f, 0.f};

    for (int k0 = 0; k0 < K; k0 += 32) {
        __syncthreads();
#pragma unroll
        for (int t = 0; t < 2; ++t) {
            const int row = w * 32 + t * 16 + l4;
            gload_lds16(hs + (size_t)(m0 + row) * K + k0 + s4 * 8,
                        (char*)Asm + w * 2048 + t * 1024);
        }
        {
            const int row = w * 16 + l4;
            gload_lds16(W + (size_t)row * K + k0 + s4 * 8,
                        (char*)Bsm + w * 1024);
        }
        __syncthreads();

        short8 a[2], b[4];
#pragma unroll
        for (int i = 0; i < 2; ++i)
            a[i] = *reinterpret_cast<const short8*>(&Asm[(w * 32 + i * 16 + lo) * 32 + hi * 8]);
#pragma unroll
        for (int j = 0; j < 4; ++j)
            b[j] = *reinterpret_cast<const short8*>(&Bsm[(j * 16 + lo) * 32 + hi * 8]);
#pragma unroll
        for (int i = 0; i < 2; ++i)
#pragma unroll
            for (int j = 0; j < 4; ++j)
                acc[i][j] = __builtin_amdgcn_mfma_f32_16x16x32_bf16(a[i], b[j], acc[i][j], 0, 0, 0);
    }

#pragma unroll
    for (int j = 0; j < 4; ++j) {
        const int col = j * 16 + lo;
        const float bv = bias[col];
#pragma unroll
        for (int i = 0; i < 2; ++i) {
            const int row0 = m0 + w * 32 + i * 16 + hi * 4;
#pragma unroll
            for (int r = 0; r < 4; ++r)
                outp[(size_t)(row0 + r) * 512 + nl + col] = f2bf(acc[i][j][r] + bv);
        }
    }
}

// ---------------------------------------------------------------------------
// Merged UP projection: one dispatch over N = 6144, K = 512.
//   n in [0,2048)    : q  = lat_q  @ Wq_up^T  + bq   -> qb (scaled, mode 2)
//   n in [2048,3072) : kn = lat_kv @ Wk_nope^T+ bkn  -> kb[:, n-2048]
//   n in [3072,4096) : kr = lat_kv @ Wk_rope^T+ bkr  -> krp[:, n-3072]
//   n in [4096,6144) : v  = lat_kv @ Wv_up^T  + bv   -> vt (transposed, mode 3)
// BM=128, BN=128, WM=2, WN=2, FM=FN=4. Grid (48, 32) = 1536 blocks.
// ---------------------------------------------------------------------------
__global__ __launch_bounds__(256)
void gemm_up(const ushort* __restrict__ latq, const ushort* __restrict__ latkv,
             const ushort* __restrict__ wqu, const ushort* __restrict__ wkn,
             const ushort* __restrict__ wkr, const ushort* __restrict__ wvu,
             const float* __restrict__ bq, const float* __restrict__ bkn,
             const float* __restrict__ bkr, const float* __restrict__ bv,
             ushort* __restrict__ qb, ushort* __restrict__ kb,
             ushort* __restrict__ krp, ushort* __restrict__ vt)
{
    constexpr int K = 512;
    __shared__ ushort Asm[128 * 32];
    __shared__ ushort Bsm[128 * 32];

    const int tid  = threadIdx.x;
    const int w    = tid >> 6;
    const int lane = tid & 63;
    const int lo   = lane & 15;
    const int hi   = lane >> 4;
    const int wm   = w >> 1;
    const int wn   = w & 1;
    const int m0   = blockIdx.y * 128;
    const int n0   = blockIdx.x * 128;
    const int l4   = lane >> 2;
    const int s4   = lane & 3;

    const ushort* A;  const ushort* W;  const float* bias;
    ushort* outp = nullptr;  int ldc = 0;  int ncol0;  int mode;
    if (n0 < 2048)      { A = latq;  W = wqu + (size_t)n0 * K;          bias = bq  + n0;
                          outp = qb;  ldc = 2048; ncol0 = n0;        mode = 2; }
    else if (n0 < 3072) { A = latkv; W = wkn + (size_t)(n0 - 2048) * K; bias = bkn + (n0 - 2048);
                          outp = kb;  ldc = 2048; ncol0 = n0 - 2048; mode = 1; }
    else if (n0 < 4096) { A = latkv; W = wkr + (size_t)(n0 - 3072) * K; bias = bkr + (n0 - 3072);
                          outp = krp; ldc = 1024; ncol0 = n0 - 3072; mode = 1; }
    else                { A = latkv; W = wvu + (size_t)(n0 - 4096) * K; bias = bv  + (n0 - 4096);
                          outp = vt;  ldc = 0;    ncol0 = n0 - 4096; mode = 3; }

    f32x4 acc[4][4];
#pragma unroll
    for (int i = 0; i < 4; ++i)
#pragma unroll
        for (int j = 0; j < 4; ++j) acc[i][j] = f32x4{0.f, 0.f, 0.f, 0.f};

    for (int k0 = 0; k0 < K; k0 += 32) {
        __syncthreads();
#pragma unroll
        for (int t = 0; t < 2; ++t) {
            const int row = w * 32 + t * 16 + l4;
            gload_lds16(A + (size_t)(m0 + row) * K + k0 + s4 * 8,
                        (char*)Asm + w * 2048 + t * 1024);
            gload_lds16(W + (size_t)row * K + k0 + s4 * 8,
                        (char*)Bsm + w * 2048 + t * 1024);
        }
        __syncthreads();

        short8 a[4], b[4];
#pragma unroll
        for (int i = 0; i < 4; ++i)
            a[i] = *reinterpret_cast<const short8*>(&Asm[(wm * 64 + i * 16 + lo) * 32 + hi * 8]);
#pragma unroll
        for (int j = 0; j < 4; ++j)
            b[j] = *reinterpret_cast<const short8*>(&Bsm[(wn * 64 + j * 16 + lo) * 32 + hi * 8]);
#pragma unroll
        for (int i = 0; i < 4; ++i)
#pragma unroll
            for (int j = 0; j < 4; ++j)
                acc[i][j] = __builtin_amdgcn_mfma_f32_16x16x32_bf16(a[i], b[j], acc[i][j], 0, 0, 0);
    }

#pragma unroll
    for (int j = 0; j < 4; ++j) {
        const int col = wn * 64 + j * 16 + lo;
        const float bb = bias[col];
#pragma unroll
        for (int i = 0; i < 4; ++i) {
            const int row0 = m0 + wm * 64 + i * 16 + hi * 4;
            if (mode == 3) {
                const int gcol = ncol0 + col;
                const int hh = gcol >> 7, dd = gcol & 127;
                const int bbi = row0 >> 11, sidx = row0 & 2047;
                ushort4 o;
                o.x = f2bf(acc[i][j][0] + bb);
                o.y = f2bf(acc[i][j][1] + bb);
                o.z = f2bf(acc[i][j][2] + bb);
                o.w = f2bf(acc[i][j][3] + bb);
                *reinterpret_cast<ushort4*>(
                    vt + (((size_t)(bbi * 16 + hh) * 128 + dd) << 11) + sidx) = o;
            } else if (mode == 2) {
#pragma unroll
                for (int r = 0; r < 4; ++r)
                    outp[(size_t)(row0 + r) * ldc + ncol0 + col] =
                        f2bf((acc[i][j][r] + bb) * QSCALE_LOG2);
            } else {
#pragma unroll
                for (int r = 0; r < 4; ++r)
                    outp[(size_t)(row0 + r) * ldc + ncol0 + col] =
                        f2bf(acc[i][j][r] + bb);
            }
        }
    }
}

// ---------------------------------------------------------------------------
// Output projection: out(f32) = ob @ Wo^T + bo.  BM=BN=128, K=2048.
// Grid (16, 32) = 512 blocks.
// ---------------------------------------------------------------------------
__global__ __launch_bounds__(256)
void gemm_out(const ushort* __restrict__ A, const ushort* __restrict__ W,
              const float* __restrict__ bias, float* __restrict__ C)
{
    constexpr int K = 2048;
    __shared__ ushort Asm[128 * 32];
    __shared__ ushort Bsm[128 * 32];

    const int tid  = threadIdx.x;
    const int w    = tid >> 6;
    const int lane = tid & 63;
    const int lo   = lane & 15;
    const int hi   = lane >> 4;
    const int wm   = w >> 1;
    const int wn   = w & 1;
    const int m0   = blockIdx.y * 128;
    const int n0   = blockIdx.x * 128;
    const int l4   = lane >> 2;
    const int s4   = lane & 3;

    f32x4 acc[4][4];
#pragma unroll
    for (int i = 0; i < 4; ++i)
#pragma unroll
        for (int j = 0; j < 4; ++j) acc[i][j] = f32x4{0.f, 0.f, 0.f, 0.f};

    for (int k0 = 0; k0 < K; k0 += 32) {
        __syncthreads();
#pragma unroll
        for (int t = 0; t < 2; ++t) {
            const int row = w * 32 + t * 16 + l4;
            gload_lds16(A + (size_t)(m0 + row) * K + k0 + s4 * 8,
                        (char*)Asm + w * 2048 + t * 1024);
            gload_lds16(W + (size_t)(n0 + row) * K + k0 + s4 * 8,
                        (char*)Bsm + w * 2048 + t * 1024);
        }
        __syncthreads();

        short8 a[4], b[4];
#pragma unroll
        for (int i = 0; i < 4; ++i)
            a[i] = *reinterpret_cast<const short8*>(&Asm[(wm * 64 + i * 16 + lo) * 32 + hi * 8]);
#pragma unroll
        for (int j = 0; j < 4; ++j)
            b[j] = *reinterpret_cast<const short8*>(&Bsm[(wn * 64 + j * 16 + lo) * 32 + hi * 8]);
#pragma unroll
        for (int i = 0; i < 4; ++i)
#pragma unroll
            for (int j = 0; j < 4; ++j)
                acc[i][j] = __builtin_amdgcn_mfma_f32_16x16x32_bf16(a[i], b[j], acc[i][j], 0, 0, 0);
    }

#pragma unroll
    for (int j = 0; j < 4; ++j) {
        const int col = n0 + wn * 64 + j * 16 + lo;
        const float bb = bias[col];
#pragma unroll
        for (int i = 0; i < 4; ++i) {
            const int row0 = m0 + wm * 64 + i * 16 + hi * 4;
#pragma unroll
            for (int r = 0; r < 4; ++r)
                C[(size_t)(row0 + r) * 2048 + col] = acc[i][j][r] + bb;
        }
    }
}

// ---------------------------------------------------------------------------
// RoPE: read pre-rotary k_rope (bf16, [4096][1024]), write rotated bf16 into
// kb cols [1024,2048). grid (4096, 2) x 256.
// ---------------------------------------------------------------------------
__global__ void rope_bf(const ushort* __restrict__ pre, ushort* __restrict__ kb)
{
    const int row = blockIdx.x;
    const int d   = blockIdx.y * 256 + threadIdx.x;   // 0..511
    const int pos = row & (S_ - 1);
    const float inv = expf((float)d * -0.017988946f); // ln(10000)/512
    const float ang = (float)pos * inv;
    const float c = cosf(ang), s = sinf(ang);
    const float x1 = bf2f(pre[(size_t)row * 1024 + d]);
    const float x2 = bf2f(pre[(size_t)row * 1024 + 512 + d]);
    kb[(size_t)row * 2048 + 1024 + d]       = f2bf(x1 * c - x2 * s);
    kb[(size_t)row * 2048 + 1024 + 512 + d] = f2bf(x1 * s + x2 * c);
}

// ---------------------------------------------------------------------------
// Flash attention, bf16 MFMA. Block = 128 q-rows for one (b,h).
// 8 waves x 16 q-rows each. KV tile = 64 keys. K LDS XOR-swizzled; Vt/P LDS
// padded to 72 bf16/row. T14 async stage split + T5 setprio + T13 defer-max.
// Softmax in exp2 domain (log2e folded into Q scale by gemm_up mode 2).
// ---------------------------------------------------------------------------
__global__ __launch_bounds__(512)
void attn_mfma(const ushort* __restrict__ Q, const ushort* __restrict__ K,
               const ushort* __restrict__ Vt, ushort* __restrict__ O)
{
    __shared__ ushort Kl[64 * 128];     // 16 KB, swizzled
    __shared__ ushort Vl[128 * 72];     // 18 KB, [d][k] padded
    __shared__ ushort Pl[8 * 16 * 72];  // 18 KB, per-wave 16 rows

    const int tid  = threadIdx.x;
    const int w    = tid >> 6;          // 0..7
    const int lane = tid & 63;
    const int lo   = lane & 15;
    const int hi   = lane >> 4;
    const int bh   = blockIdx.y;
    const int b    = bh >> 4;
    const int q0   = blockIdx.x * 128;
    const size_t headoff = (size_t)(bh & 15) * HD_;

    // Q fragments (pre-scaled by 1/sqrt(128)*log2e)
    short8 aq[4];
    {
        const ushort* qrow = Q + (size_t)(b * S_ + q0 + w * 16 + lo) * H_ + headoff;
#pragma unroll
        for (int kd = 0; kd < 4; ++kd)
            aq[kd] = *reinterpret_cast<const short8*>(qrow + kd * 32 + hi * 8);
    }

    f32x4 oacc[8];
#pragma unroll
    for (int fd = 0; fd < 8; ++fd) oacc[fd] = f32x4{0.f, 0.f, 0.f, 0.f};
    float m_run[4], l_run[4];
#pragma unroll
    for (int r = 0; r < 4; ++r) { m_run[r] = -INFINITY; l_run[r] = 0.f; }

    const ushort* kbase = K  + (size_t)(b * S_) * H_ + headoff;
    const ushort* vbase = Vt + (size_t)bh * 128 * S_;

    short8 kst[2], vst[2];
    auto issue_loads = [&](int kt) {
#pragma unroll
        for (int r = 0; r < 2; ++r) {
            const int c = r * 512 + tid;       // 0..1023 16B chunks
            kst[r] = *reinterpret_cast<const short8*>(
                kbase + (size_t)(kt * 64 + (c >> 4)) * H_ + (c & 15) * 8);
            vst[r] = *reinterpret_cast<const short8*>(
                vbase + (size_t)(c >> 3) * S_ + kt * 64 + (c & 7) * 8);
        }
    };
    auto write_lds = [&]() {
#pragma unroll
        for (int r = 0; r < 2; ++r) {
            const int c = r * 512 + tid;
            const int key = c >> 4, slot = c & 15;
            *reinterpret_cast<short8*>(
                (char*)Kl + key * 256 + ((slot * 16) ^ ((key & 7) << 4))) = kst[r];
            *reinterpret_cast<short8*>(
                (char*)Vl + (c >> 3) * 144 + (c & 7) * 16) = vst[r];
        }
    };

    issue_loads(0);
    write_lds();
    __syncthreads();

    const int swz = (lo & 7) << 4;

    for (int kt = 0; kt < S_ / 64; ++kt) {
        if (kt + 1 < S_ / 64) issue_loads(kt + 1);   // in flight across compute

        // ---- S = Q K^T  (16q x 64k per wave), exp2 domain ----
        f32x4 s[4];
#pragma unroll
        for (int fn = 0; fn < 4; ++fn) s[fn] = f32x4{0.f, 0.f, 0.f, 0.f};

        __builtin_amdgcn_s_setprio(1);
#pragma unroll
        for (int fn = 0; fn < 4; ++fn) {
            const int kbyte = (fn * 16 + lo) * 256;
#pragma unroll
            for (int kd = 0; kd < 4; ++kd) {
                short8 bk = *reinterpret_cast<const short8*>(
                    (const char*)Kl + kbyte + ((kd * 64 + hi * 16) ^ swz));
                s[fn] = __builtin_amdgcn_mfma_f32_16x16x32_bf16(aq[kd], bk, s[fn], 0, 0, 0);
            }
        }
        __builtin_amdgcn_s_setprio(0);

        // ---- online softmax with defer-max (T13, THR=8 in log2 domain) ----
        float f_r[4];
        bool resc = false;
#pragma unroll
        for (int r = 0; r < 4; ++r) {
            const float s0 = s[0][r], s1 = s[1][r], s2 = s[2][r], s3 = s[3][r];
            float mx = fmaxf(fmaxf(s0, s1), fmaxf(s2, s3));
            mx = fmaxf(mx, __shfl_xor(mx, 1));
            mx = fmaxf(mx, __shfl_xor(mx, 2));
            mx = fmaxf(mx, __shfl_xor(mx, 4));
            mx = fmaxf(mx, __shfl_xor(mx, 8));
            if (mx - m_run[r] > 8.0f) {
                f_r[r] = exp2f(m_run[r] - mx);
                m_run[r] = mx;
                resc = true;
            } else {
                f_r[r] = 1.0f;
            }
            const float p0 = exp2f(s0 - m_run[r]), p1 = exp2f(s1 - m_run[r]),
                        p2 = exp2f(s2 - m_run[r]), p3 = exp2f(s3 - m_run[r]);
            float ls = p0 + p1 + p2 + p3;
            ls += __shfl_xor(ls, 1);
            ls += __shfl_xor(ls, 2);
            ls += __shfl_xor(ls, 4);
            ls += __shfl_xor(ls, 8);
            l_run[r] = l_run[r] * f_r[r] + ls;
            ushort* prow = &Pl[(size_t)(w * 16 + hi * 4 + r) * 72 + lo];
            prow[0]  = f2bf(p0);
            prow[16] = f2bf(p1);
            prow[32] = f2bf(p2);
            prow[48] = f2bf(p3);
        }

        if (__any((int)resc)) {
#pragma unroll
            for (int fd = 0; fd < 8; ++fd)
#pragma unroll
                for (int r = 0; r < 4; ++r)
                    oacc[fd][r] *= f_r[r];
        }

        // ---- O += P V ----
        __builtin_amdgcn_s_setprio(1);
#pragma unroll
        for (int ks = 0; ks < 2; ++ks) {
            short8 pa = *reinterpret_cast<const short8*>(
                (const char*)Pl + (w * 16 + lo) * 144 + ks * 64 + hi * 16);
#pragma unroll
            for (int fd = 0; fd < 8; ++fd) {
                short8 bv = *reinterpret_cast<const short8*>(
                    (const char*)Vl + (fd * 16 + lo) * 144 + ks * 64 + hi * 16);
                oacc[fd] = __builtin_amdgcn_mfma_f32_16x16x32_bf16(pa, bv, oacc[fd], 0, 0, 0);
            }
        }
        __builtin_amdgcn_s_setprio(0);

        __syncthreads();                 // all waves done reading Kl/Vl/Pl
        if (kt + 1 < S_ / 64) {
            write_lds();                 // vmcnt wait inserted by compiler
            __syncthreads();
        }
    }

    // ---- normalize + store bf16 ----
#pragma unroll
    for (int r = 0; r < 4; ++r) {
        const float inv = 1.0f / l_run[r];
        ushort* orow = O + (size_t)(b * S_ + q0 + w * 16 + hi * 4 + r) * H_
                         + headoff + lo;
#pragma unroll
        for (int fd = 0; fd < 8; ++fd)
            orow[fd * 16] = f2bf(oacc[fd][r] * inv);
    }
}

// ---------------------------------------------------------------------------
// Launch
// ---------------------------------------------------------------------------
extern "C" void kernel_launch(void* const* d_in, const int* in_sizes, int n_in,
                              void* d_out, int out_size, void* d_ws, size_t ws_size,
                              hipStream_t stream)
{
    const float* hs       = (const float*)d_in[0];
    const float* Wq_down  = (const float*)d_in[1];
    const float* bq_down  = (const float*)d_in[2];
    const float* Wkv_down = (const float*)d_in[3];
    const float* bkv_down = (const float*)d_in[4];
    const float* Wq_up    = (const float*)d_in[5];
    const float* bq_up    = (const float*)d_in[6];
    const float* Wk_nope  = (const float*)d_in[7];
    const float* bk_nope  = (const float*)d_in[8];
    const float* Wk_rope  = (const float*)d_in[9];
    const float* bk_rope  = (const float*)d_in[10];
    const float* Wv_up    = (const float*)d_in[11];
    const float* bv_up    = (const float*)d_in[12];
    const float* Wo       = (const float*)d_in[13];
    const float* bo       = (const float*)d_in[14];
    float* out = (float*)d_out;

    // Workspace layout in ushort (bf16) units. Total ~120 MB.
    ushort* ws = (ushort*)d_ws;
    ushort* hs_bf   = ws;                                // 8,388,608
    ushort* wqd_bf  = hs_bf  + (size_t)8388608;          // 1,048,576
    ushort* wkvd_bf = wqd_bf + (size_t)1048576;          // 1,048,576
    ushort* wqu_bf  = wkvd_bf+ (size_t)1048576;          // 1,048,576
    ushort* wkn_bf  = wqu_bf + (size_t)1048576;          //   524,288
    ushort* wkr_bf  = wkn_bf + (size_t)524288;           //   524,288
    ushort* wvu_bf  = wkr_bf + (size_t)524288;           // 1,048,576
    ushort* wo_bf   = wvu_bf + (size_t)1048576;          // 4,194,304
    ushort* lat_q   = wo_bf  + (size_t)4194304;          // 2,097,152
    ushort* lat_kv  = lat_q  + (size_t)2097152;          // 2,097,152
    ushort* qb      = lat_kv + (size_t)2097152;          // 8,388,608
    ushort* kb      = qb     + (size_t)8388608;          // 8,388,608
    ushort* krp     = kb     + (size_t)8388608;          // 4,194,304
    ushort* vt      = krp    + (size_t)4194304;          // 8,388,608
    ushort* ob      = vt     + (size_t)8388608;          // 8,388,608

    const int M = B_ * S_;   // 4096

    // ---- fused casts (1 launch) ----
    CastParams cp;
    cp.seg[0] = { hs,       hs_bf,   8388608u / 4 };
    cp.seg[1] = { Wq_down,  wqd_bf,  1048576u / 4 };
    cp.seg[2] = { Wkv_down, wkvd_bf, 1048576u / 4 };
    cp.seg[3] = { Wq_up,    wqu_bf,  1048576u / 4 };
    cp.seg[4] = { Wk_nope,  wkn_bf,   524288u / 4 };
    cp.seg[5] = { Wk_rope,  wkr_bf,   524288u / 4 };
    cp.seg[6] = { Wv_up,    wvu_bf,  1048576u / 4 };
    cp.seg[7] = { Wo,       wo_bf,   4194304u / 4 };
    cp.total4 = (8388608u + 1048576u * 4 + 524288u * 2 + 4194304u) / 4;
    cast_all<<<(cp.total4 + 255) / 256, 256, 0, stream>>>(cp);

    // ---- merged down projections: N=1024, K=2048, 512 blocks ----
    gemm_down<<<dim3(16, 32), 256, 0, stream>>>(
        hs_bf, wqd_bf, wkvd_bf, bq_down, bkv_down, lat_q, lat_kv);

    // ---- merged up projections: N=6144, K=512, 1536 blocks ----
    gemm_up<<<dim3(48, 32), 256, 0, stream>>>(
        lat_q, lat_kv, wqu_bf, wkn_bf, wkr_bf, wvu_bf,
        bq_up, bk_nope, bk_rope, bv_up, qb, kb, krp, vt);

    // ---- rope into kb[:,1024:2048) ----
    rope_bf<<<dim3(M, 2), 256, 0, stream>>>(krp, kb);

    // ---- attention: 512 threads, 8 waves x 16 q-rows ----
    attn_mfma<<<dim3(S_ / 128, B_ * NH_), 512, 0, stream>>>(qb, kb, vt, ob);

    // ---- output projection (fp32 out), 512 blocks ----
    gemm_out<<<dim3(16, 32), 256, 0, stream>>>(ob, wo_bf, bo, out);
}

// Round 7
// 380.450 us; speedup vs baseline: 8.3982x; 1.0796x over previous
//
#include <hip/hip_runtime.h>
#include <math.h>

#define B_  2
#define S_  2048
#define H_  2048
#define NH_ 16
#define HD_ 128

typedef __attribute__((ext_vector_type(8))) short short8;
typedef __attribute__((ext_vector_type(4))) float f32x4;

#define AS1 __attribute__((address_space(1)))
#define AS3 __attribute__((address_space(3)))

// 1/sqrt(128) * log2(e)  (softmax runs in exp2 domain)
#define QSCALE_LOG2 (0.08838834764831845f * 1.4426950408889634f)

__device__ __forceinline__ ushort f2bf(float f) {
    union { float f; unsigned u; } x; x.f = f;
    unsigned r = (x.u + 0x7FFF + ((x.u >> 16) & 1)) >> 16;
    return (ushort)r;
}
__device__ __forceinline__ float bf2f(ushort u) {
    union { unsigned u; float f; } x; x.u = ((unsigned)u) << 16;
    return x.f;
}
__device__ __forceinline__ unsigned cvt_pk_bf16(float a, float b) {
    unsigned r;  // D[15:0]=bf16(S0)=a, D[31:16]=bf16(S1)=b
    asm("v_cvt_pk_bf16_f32 %0, %1, %2" : "=v"(r) : "v"(a), "v"(b));
    return r;
}
__device__ __forceinline__ void gload_lds16(const void* g, void* l) {
    __builtin_amdgcn_global_load_lds((const AS1 void*)g, (AS3 void*)l, 16, 0, 0);
}

// ---------------------------------------------------------------------------
// Fused fp32 -> bf16 cast over 8 segments
// ---------------------------------------------------------------------------
struct CastSeg { const float* src; ushort* dst; unsigned n4; };
struct CastParams { CastSeg seg[8]; unsigned total4; };

__global__ __launch_bounds__(256)
void cast_all(CastParams p)
{
    unsigned i = blockIdx.x * 256 + threadIdx.x;   // float4 index
    if (i >= p.total4) return;
#pragma unroll
    for (int s = 0; s < 8; ++s) {
        if (i < p.seg[s].n4) {
            const float4 v = reinterpret_cast<const float4*>(p.seg[s].src)[i];
            ushort4 o;
            o.x = f2bf(v.x); o.y = f2bf(v.y); o.z = f2bf(v.z); o.w = f2bf(v.w);
            reinterpret_cast<ushort4*>(p.seg[s].dst)[i] = o;
            return;
        }
        i -= p.seg[s].n4;
    }
}

// ---------------------------------------------------------------------------
// Merged DOWN projection: both latents, N=1024 (cols 0..511 -> lat_q,
// 512..1023 -> lat_kv). BM=128, BN=64, K=2048. Grid (16,32)=512 blocks.
// ---------------------------------------------------------------------------
__global__ __launch_bounds__(256)
void gemm_down(const ushort* __restrict__ hs,
               const ushort* __restrict__ wqd, const ushort* __restrict__ wkvd,
               const float* __restrict__ bqd, const float* __restrict__ bkvd,
               ushort* __restrict__ latq, ushort* __restrict__ latkv)
{
    constexpr int K = 2048;
    __shared__ ushort Asm[128 * 32];
    __shared__ ushort Bsm[64 * 32];

    const int tid  = threadIdx.x;
    const int w    = tid >> 6;
    const int lane = tid & 63;
    const int lo   = lane & 15;
    const int hi   = lane >> 4;
    const int m0   = blockIdx.y * 128;
    const int n0   = blockIdx.x * 64;
    const int l4   = lane >> 2;
    const int s4   = lane & 3;

    const int seg = n0 >> 9;
    const int nl  = n0 & 511;
    const ushort* W    = (seg ? wkvd : wqd) + (size_t)nl * K;
    const float*  bias = (seg ? bkvd : bqd) + nl;
    ushort*       outp = seg ? latkv : latq;

    f32x4 acc[2][4];
#pragma unroll
    for (int i = 0; i < 2; ++i)
#pragma unroll
        for (int j = 0; j < 4; ++j) acc[i][j] = f32x4{0.f, 0.f, 0.f, 0.f};

    for (int k0 = 0; k0 < K; k0 += 32) {
        __syncthreads();
#pragma unroll
        for (int t = 0; t < 2; ++t) {
            const int row = w * 32 + t * 16 + l4;
            gload_lds16(hs + (size_t)(m0 + row) * K + k0 + s4 * 8,
                        (char*)Asm + w * 2048 + t * 1024);
        }
        {
            const int row = w * 16 + l4;
            gload_lds16(W + (size_t)row * K + k0 + s4 * 8,
                        (char*)Bsm + w * 1024);
        }
        __syncthreads();

        short8 a[2], b[4];
#pragma unroll
        for (int i = 0; i < 2; ++i)
            a[i] = *reinterpret_cast<const short8*>(&Asm[(w * 32 + i * 16 + lo) * 32 + hi * 8]);
#pragma unroll
        for (int j = 0; j < 4; ++j)
            b[j] = *reinterpret_cast<const short8*>(&Bsm[(j * 16 + lo) * 32 + hi * 8]);
#pragma unroll
        for (int i = 0; i < 2; ++i)
#pragma unroll
            for (int j = 0; j < 4; ++j)
                acc[i][j] = __builtin_amdgcn_mfma_f32_16x16x32_bf16(a[i], b[j], acc[i][j], 0, 0, 0);
    }

#pragma unroll
    for (int j = 0; j < 4; ++j) {
        const int col = j * 16 + lo;
        const float bv = bias[col];
#pragma unroll
        for (int i = 0; i < 2; ++i) {
            const int row0 = m0 + w * 32 + i * 16 + hi * 4;
#pragma unroll
            for (int r = 0; r < 4; ++r)
                outp[(size_t)(row0 + r) * 512 + nl + col] = f2bf(acc[i][j][r] + bv);
        }
    }
}

// ---------------------------------------------------------------------------
// Merged UP projection: N = 6144, K = 512.
//   [0,2048)    : q  -> qb (scaled by QSCALE_LOG2, mode 2)
//   [2048,3072) : k_nope -> kb
//   [3072,4096) : k_rope(pre) -> krp
//   [4096,6144) : v  -> vt transposed [bh][d][tok] (mode 3)
// Grid (48, 32) = 1536 blocks.
// ---------------------------------------------------------------------------
__global__ __launch_bounds__(256)
void gemm_up(const ushort* __restrict__ latq, const ushort* __restrict__ latkv,
             const ushort* __restrict__ wqu, const ushort* __restrict__ wkn,
             const ushort* __restrict__ wkr, const ushort* __restrict__ wvu,
             const float* __restrict__ bq, const float* __restrict__ bkn,
             const float* __restrict__ bkr, const float* __restrict__ bv,
             ushort* __restrict__ qb, ushort* __restrict__ kb,
             ushort* __restrict__ krp, ushort* __restrict__ vt)
{
    constexpr int K = 512;
    __shared__ ushort Asm[128 * 32];
    __shared__ ushort Bsm[128 * 32];

    const int tid  = threadIdx.x;
    const int w    = tid >> 6;
    const int lane = tid & 63;
    const int lo   = lane & 15;
    const int hi   = lane >> 4;
    const int wm   = w >> 1;
    const int wn   = w & 1;
    const int m0   = blockIdx.y * 128;
    const int n0   = blockIdx.x * 128;
    const int l4   = lane >> 2;
    const int s4   = lane & 3;

    const ushort* A;  const ushort* W;  const float* bias;
    ushort* outp = nullptr;  int ldc = 0;  int ncol0;  int mode;
    if (n0 < 2048)      { A = latq;  W = wqu + (size_t)n0 * K;          bias = bq  + n0;
                          outp = qb;  ldc = 2048; ncol0 = n0;        mode = 2; }
    else if (n0 < 3072) { A = latkv; W = wkn + (size_t)(n0 - 2048) * K; bias = bkn + (n0 - 2048);
                          outp = kb;  ldc = 2048; ncol0 = n0 - 2048; mode = 1; }
    else if (n0 < 4096) { A = latkv; W = wkr + (size_t)(n0 - 3072) * K; bias = bkr + (n0 - 3072);
                          outp = krp; ldc = 1024; ncol0 = n0 - 3072; mode = 1; }
    else                { A = latkv; W = wvu + (size_t)(n0 - 4096) * K; bias = bv  + (n0 - 4096);
                          outp = vt;  ldc = 0;    ncol0 = n0 - 4096; mode = 3; }

    f32x4 acc[4][4];
#pragma unroll
    for (int i = 0; i < 4; ++i)
#pragma unroll
        for (int j = 0; j < 4; ++j) acc[i][j] = f32x4{0.f, 0.f, 0.f, 0.f};

    for (int k0 = 0; k0 < K; k0 += 32) {
        __syncthreads();
#pragma unroll
        for (int t = 0; t < 2; ++t) {
            const int row = w * 32 + t * 16 + l4;
            gload_lds16(A + (size_t)(m0 + row) * K + k0 + s4 * 8,
                        (char*)Asm + w * 2048 + t * 1024);
            gload_lds16(W + (size_t)row * K + k0 + s4 * 8,
                        (char*)Bsm + w * 2048 + t * 1024);
        }
        __syncthreads();

        short8 a[4], b[4];
#pragma unroll
        for (int i = 0; i < 4; ++i)
            a[i] = *reinterpret_cast<const short8*>(&Asm[(wm * 64 + i * 16 + lo) * 32 + hi * 8]);
#pragma unroll
        for (int j = 0; j < 4; ++j)
            b[j] = *reinterpret_cast<const short8*>(&Bsm[(wn * 64 + j * 16 + lo) * 32 + hi * 8]);
#pragma unroll
        for (int i = 0; i < 4; ++i)
#pragma unroll
            for (int j = 0; j < 4; ++j)
                acc[i][j] = __builtin_amdgcn_mfma_f32_16x16x32_bf16(a[i], b[j], acc[i][j], 0, 0, 0);
    }

#pragma unroll
    for (int j = 0; j < 4; ++j) {
        const int col = wn * 64 + j * 16 + lo;
        const float bb = bias[col];
#pragma unroll
        for (int i = 0; i < 4; ++i) {
            const int row0 = m0 + wm * 64 + i * 16 + hi * 4;
            if (mode == 3) {
                const int gcol = ncol0 + col;
                const int hh = gcol >> 7, dd = gcol & 127;
                const int bbi = row0 >> 11, sidx = row0 & 2047;
                ushort4 o;
                o.x = f2bf(acc[i][j][0] + bb);
                o.y = f2bf(acc[i][j][1] + bb);
                o.z = f2bf(acc[i][j][2] + bb);
                o.w = f2bf(acc[i][j][3] + bb);
                *reinterpret_cast<ushort4*>(
                    vt + (((size_t)(bbi * 16 + hh) * 128 + dd) << 11) + sidx) = o;
            } else if (mode == 2) {
#pragma unroll
                for (int r = 0; r < 4; ++r)
                    outp[(size_t)(row0 + r) * ldc + ncol0 + col] =
                        f2bf((acc[i][j][r] + bb) * QSCALE_LOG2);
            } else {
#pragma unroll
                for (int r = 0; r < 4; ++r)
                    outp[(size_t)(row0 + r) * ldc + ncol0 + col] =
                        f2bf(acc[i][j][r] + bb);
            }
        }
    }
}

// ---------------------------------------------------------------------------
// Output projection: out(f32) = ob @ Wo^T + bo.  BM=128, BN=64, K=2048.
// Grid (32, 32) = 1024 blocks (4/CU; was 512 = grid-starved).
// ---------------------------------------------------------------------------
__global__ __launch_bounds__(256)
void gemm_out(const ushort* __restrict__ A, const ushort* __restrict__ W,
              const float* __restrict__ bias, float* __restrict__ C)
{
    constexpr int K = 2048;
    __shared__ ushort Asm[128 * 32];
    __shared__ ushort Bsm[64 * 32];

    const int tid  = threadIdx.x;
    const int w    = tid >> 6;
    const int lane = tid & 63;
    const int lo   = lane & 15;
    const int hi   = lane >> 4;
    const int m0   = blockIdx.y * 128;
    const int n0   = blockIdx.x * 64;
    const int l4   = lane >> 2;
    const int s4   = lane & 3;

    f32x4 acc[2][4];
#pragma unroll
    for (int i = 0; i < 2; ++i)
#pragma unroll
        for (int j = 0; j < 4; ++j) acc[i][j] = f32x4{0.f, 0.f, 0.f, 0.f};

    for (int k0 = 0; k0 < K; k0 += 32) {
        __syncthreads();
#pragma unroll
        for (int t = 0; t < 2; ++t) {
            const int row = w * 32 + t * 16 + l4;
            gload_lds16(A + (size_t)(m0 + row) * K + k0 + s4 * 8,
                        (char*)Asm + w * 2048 + t * 1024);
        }
        {
            const int row = w * 16 + l4;
            gload_lds16(W + (size_t)(n0 + row) * K + k0 + s4 * 8,
                        (char*)Bsm + w * 1024);
        }
        __syncthreads();

        short8 a[2], b[4];
#pragma unroll
        for (int i = 0; i < 2; ++i)
            a[i] = *reinterpret_cast<const short8*>(&Asm[(w * 32 + i * 16 + lo) * 32 + hi * 8]);
#pragma unroll
        for (int j = 0; j < 4; ++j)
            b[j] = *reinterpret_cast<const short8*>(&Bsm[(j * 16 + lo) * 32 + hi * 8]);
#pragma unroll
        for (int i = 0; i < 2; ++i)
#pragma unroll
            for (int j = 0; j < 4; ++j)
                acc[i][j] = __builtin_amdgcn_mfma_f32_16x16x32_bf16(a[i], b[j], acc[i][j], 0, 0, 0);
    }

#pragma unroll
    for (int j = 0; j < 4; ++j) {
        const int col = n0 + j * 16 + lo;
        const float bb = bias[col];
#pragma unroll
        for (int i = 0; i < 2; ++i) {
            const int row0 = m0 + w * 32 + i * 16 + hi * 4;
#pragma unroll
            for (int r = 0; r < 4; ++r)
                C[(size_t)(row0 + r) * 2048 + col] = acc[i][j][r] + bb;
        }
    }
}

// ---------------------------------------------------------------------------
// RoPE: pre-rotary k_rope (bf16 [4096][1024]) -> kb cols [1024,2048).
// ---------------------------------------------------------------------------
__global__ void rope_bf(const ushort* __restrict__ pre, ushort* __restrict__ kb)
{
    const int row = blockIdx.x;
    const int d   = blockIdx.y * 256 + threadIdx.x;   // 0..511
    const int pos = row & (S_ - 1);
    const float inv = expf((float)d * -0.017988946f); // ln(10000)/512
    const float ang = (float)pos * inv;
    const float c = cosf(ang), s = sinf(ang);
    const float x1 = bf2f(pre[(size_t)row * 1024 + d]);
    const float x2 = bf2f(pre[(size_t)row * 1024 + 512 + d]);
    kb[(size_t)row * 2048 + 1024 + d]       = f2bf(x1 * c - x2 * s);
    kb[(size_t)row * 2048 + 1024 + 512 + d] = f2bf(x1 * s + x2 * c);
}

// ---------------------------------------------------------------------------
// Flash attention, bf16 MFMA, SWAPPED QK^T (T12-lite).
// Block = 128 q-rows for one (b,h); 8 waves x 16 q-rows. KV tile = 64.
// QK^T computed as mfma(K_frag, Q_frag) -> lane holds P[16 keys][q=lane&15]:
// row reduce = 15 local ops + 2 shfl_xor; m/l are per-thread scalars.
// P packed with v_cvt_pk_bf16_f32, written as 4 x ds_write_b64.
// ---------------------------------------------------------------------------
__global__ __launch_bounds__(512)
void attn_mfma(const ushort* __restrict__ Q, const ushort* __restrict__ K,
               const ushort* __restrict__ Vt, ushort* __restrict__ O)
{
    __shared__ ushort Kl[64 * 128];     // 16 KB, swizzled 256B rows
    __shared__ ushort Vl[128 * 72];     // 18 KB, [d][k] padded
    __shared__ ushort Pl[8 * 16 * 72];  // 18 KB, per-wave 16 rows

    const int tid  = threadIdx.x;
    const int w    = tid >> 6;          // 0..7
    const int lane = tid & 63;
    const int lo   = lane & 15;
    const int hi   = lane >> 4;
    const int bh   = blockIdx.y;
    const int b    = bh >> 4;
    const int q0   = blockIdx.x * 128;
    const size_t headoff = (size_t)(bh & 15) * HD_;

    // Q fragments (pre-scaled by 1/sqrt(128)*log2e); lane lo = q-row.
    short8 aq[4];
    {
        const ushort* qrow = Q + (size_t)(b * S_ + q0 + w * 16 + lo) * H_ + headoff;
#pragma unroll
        for (int kd = 0; kd < 4; ++kd)
            aq[kd] = *reinterpret_cast<const short8*>(qrow + kd * 32 + hi * 8);
    }

    f32x4 oacc[8];
#pragma unroll
    for (int fd = 0; fd < 8; ++fd) oacc[fd] = f32x4{0.f, 0.f, 0.f, 0.f};
    float m_run = -INFINITY, l_run = 0.f;      // for q-row = lo

    const ushort* kbase = K  + (size_t)(b * S_) * H_ + headoff;
    const ushort* vbase = Vt + (size_t)bh * 128 * S_;

    short8 kst[2], vst[2];
    auto issue_loads = [&](int kt) {
#pragma unroll
        for (int r = 0; r < 2; ++r) {
            const int c = r * 512 + tid;       // 0..1023 16B chunks
            kst[r] = *reinterpret_cast<const short8*>(
                kbase + (size_t)(kt * 64 + (c >> 4)) * H_ + (c & 15) * 8);
            vst[r] = *reinterpret_cast<const short8*>(
                vbase + (size_t)(c >> 3) * S_ + kt * 64 + (c & 7) * 8);
        }
    };
    auto write_lds = [&]() {
#pragma unroll
        for (int r = 0; r < 2; ++r) {
            const int c = r * 512 + tid;
            const int key = c >> 4, slot = c & 15;
            *reinterpret_cast<short8*>(
                (char*)Kl + key * 256 + ((slot * 16) ^ ((key & 7) << 4))) = kst[r];
            *reinterpret_cast<short8*>(
                (char*)Vl + (c >> 3) * 144 + (c & 7) * 16) = vst[r];
        }
    };

    issue_loads(0);
    write_lds();
    __syncthreads();

    const int swz = (lo & 7) << 4;

    for (int kt = 0; kt < S_ / 64; ++kt) {
        if (kt + 1 < S_ / 64) issue_loads(kt + 1);   // in flight across compute

        // ---- S^T = K Q^T: st[fn][r] = P[key = fn*16 + hi*4 + r][q = lo] ----
        f32x4 st[4];
#pragma unroll
        for (int fn = 0; fn < 4; ++fn) st[fn] = f32x4{0.f, 0.f, 0.f, 0.f};

        __builtin_amdgcn_s_setprio(1);
#pragma unroll
        for (int fn = 0; fn < 4; ++fn) {
            const int kbyte = (fn * 16 + lo) * 256;
#pragma unroll
            for (int kd = 0; kd < 4; ++kd) {
                short8 bk = *reinterpret_cast<const short8*>(
                    (const char*)Kl + kbyte + ((kd * 64 + hi * 16) ^ swz));
                st[fn] = __builtin_amdgcn_mfma_f32_16x16x32_bf16(bk, aq[kd], st[fn], 0, 0, 0);
            }
        }
        __builtin_amdgcn_s_setprio(0);

        // ---- softmax for q = lo (16 local keys, then cross-hi combine) ----
        float mx = st[0][0];
#pragma unroll
        for (int fn = 0; fn < 4; ++fn)
#pragma unroll
            for (int r = 0; r < 4; ++r) mx = fmaxf(mx, st[fn][r]);
        mx = fmaxf(mx, __shfl_xor(mx, 16));
        mx = fmaxf(mx, __shfl_xor(mx, 32));

        float fscale = 1.0f;
        bool resc = false;
        if (mx > m_run + 8.0f) {            // defer-max (T13, log2 domain)
            fscale = exp2f(m_run - mx);
            m_run = mx;
            resc = true;
        }

        float p[4][4];
        float ls = 0.f;
#pragma unroll
        for (int fn = 0; fn < 4; ++fn)
#pragma unroll
            for (int r = 0; r < 4; ++r) {
                p[fn][r] = exp2f(st[fn][r] - m_run);
                ls += p[fn][r];
            }
        ls += __shfl_xor(ls, 16);
        ls += __shfl_xor(ls, 32);
        l_run = l_run * fscale + ls;

        // ---- pack P (bf16) and write 4 x b64: keys fn*16+hi*4..+3, row lo --
        {
            char* prow = (char*)Pl + (w * 16 + lo) * 144 + hi * 8;
#pragma unroll
            for (int fn = 0; fn < 4; ++fn) {
                uint2 u;
                u.x = cvt_pk_bf16(p[fn][0], p[fn][1]);
                u.y = cvt_pk_bf16(p[fn][2], p[fn][3]);
                *reinterpret_cast<uint2*>(prow + fn * 32) = u;
            }
        }

        // ---- rescale O (rows hi*4+r; factors live in lanes hi*4+r) ----
        if (__any((int)resc)) {
#pragma unroll
            for (int r = 0; r < 4; ++r) {
                const float fr = __shfl(fscale, hi * 4 + r);
#pragma unroll
                for (int fd = 0; fd < 8; ++fd) oacc[fd][r] *= fr;
            }
        }

        // ---- O += P V ----
        __builtin_amdgcn_s_setprio(1);
#pragma unroll
        for (int ks = 0; ks < 2; ++ks) {
            short8 pa = *reinterpret_cast<const short8*>(
                (const char*)Pl + (w * 16 + lo) * 144 + ks * 64 + hi * 16);
#pragma unroll
            for (int fd = 0; fd < 8; ++fd) {
                short8 bv = *reinterpret_cast<const short8*>(
                    (const char*)Vl + (fd * 16 + lo) * 144 + ks * 64 + hi * 16);
                oacc[fd] = __builtin_amdgcn_mfma_f32_16x16x32_bf16(pa, bv, oacc[fd], 0, 0, 0);
            }
        }
        __builtin_amdgcn_s_setprio(0);

        __syncthreads();                 // all waves done reading Kl/Vl
        if (kt + 1 < S_ / 64) {
            write_lds();                 // vmcnt wait inserted by compiler
            __syncthreads();
        }
    }

    // ---- normalize + store bf16 (l for row x lives in lane x) ----
#pragma unroll
    for (int r = 0; r < 4; ++r) {
        const float lr  = __shfl(l_run, hi * 4 + r);
        const float inv = 1.0f / lr;
        ushort* orow = O + (size_t)(b * S_ + q0 + w * 16 + hi * 4 + r) * H_
                         + headoff + lo;
#pragma unroll
        for (int fd = 0; fd < 8; ++fd)
            orow[fd * 16] = f2bf(oacc[fd][r] * inv);
    }
}

// ---------------------------------------------------------------------------
// Launch
// ---------------------------------------------------------------------------
extern "C" void kernel_launch(void* const* d_in, const int* in_sizes, int n_in,
                              void* d_out, int out_size, void* d_ws, size_t ws_size,
                              hipStream_t stream)
{
    const float* hs       = (const float*)d_in[0];
    const float* Wq_down  = (const float*)d_in[1];
    const float* bq_down  = (const float*)d_in[2];
    const float* Wkv_down = (const float*)d_in[3];
    const float* bkv_down = (const float*)d_in[4];
    const float* Wq_up    = (const float*)d_in[5];
    const float* bq_up    = (const float*)d_in[6];
    const float* Wk_nope  = (const float*)d_in[7];
    const float* bk_nope  = (const float*)d_in[8];
    const float* Wk_rope  = (const float*)d_in[9];
    const float* bk_rope  = (const float*)d_in[10];
    const float* Wv_up    = (const float*)d_in[11];
    const float* bv_up    = (const float*)d_in[12];
    const float* Wo       = (const float*)d_in[13];
    const float* bo       = (const float*)d_in[14];
    float* out = (float*)d_out;

    // Workspace layout in ushort (bf16) units. Total ~120 MB.
    ushort* ws = (ushort*)d_ws;
    ushort* hs_bf   = ws;                                // 8,388,608
    ushort* wqd_bf  = hs_bf  + (size_t)8388608;          // 1,048,576
    ushort* wkvd_bf = wqd_bf + (size_t)1048576;          // 1,048,576
    ushort* wqu_bf  = wkvd_bf+ (size_t)1048576;          // 1,048,576
    ushort* wkn_bf  = wqu_bf + (size_t)1048576;          //   524,288
    ushort* wkr_bf  = wkn_bf + (size_t)524288;           //   524,288
    ushort* wvu_bf  = wkr_bf + (size_t)524288;           // 1,048,576
    ushort* wo_bf   = wvu_bf + (size_t)1048576;          // 4,194,304
    ushort* lat_q   = wo_bf  + (size_t)4194304;          // 2,097,152
    ushort* lat_kv  = lat_q  + (size_t)2097152;          // 2,097,152
    ushort* qb      = lat_kv + (size_t)2097152;          // 8,388,608
    ushort* kb      = qb     + (size_t)8388608;          // 8,388,608
    ushort* krp     = kb     + (size_t)8388608;          // 4,194,304
    ushort* vt      = krp    + (size_t)4194304;          // 8,388,608
    ushort* ob      = vt     + (size_t)8388608;          // 8,388,608

    const int M = B_ * S_;   // 4096

    // ---- fused casts (1 launch) ----
    CastParams cp;
    cp.seg[0] = { hs,       hs_bf,   8388608u / 4 };
    cp.seg[1] = { Wq_down,  wqd_bf,  1048576u / 4 };
    cp.seg[2] = { Wkv_down, wkvd_bf, 1048576u / 4 };
    cp.seg[3] = { Wq_up,    wqu_bf,  1048576u / 4 };
    cp.seg[4] = { Wk_nope,  wkn_bf,   524288u / 4 };
    cp.seg[5] = { Wk_rope,  wkr_bf,   524288u / 4 };
    cp.seg[6] = { Wv_up,    wvu_bf,  1048576u / 4 };
    cp.seg[7] = { Wo,       wo_bf,   4194304u / 4 };
    cp.total4 = (8388608u + 1048576u * 4 + 524288u * 2 + 4194304u) / 4;
    cast_all<<<(cp.total4 + 255) / 256, 256, 0, stream>>>(cp);

    // ---- merged down projections: N=1024, K=2048, 512 blocks ----
    gemm_down<<<dim3(16, 32), 256, 0, stream>>>(
        hs_bf, wqd_bf, wkvd_bf, bq_down, bkv_down, lat_q, lat_kv);

    // ---- merged up projections: N=6144, K=512, 1536 blocks ----
    gemm_up<<<dim3(48, 32), 256, 0, stream>>>(
        lat_q, lat_kv, wqu_bf, wkn_bf, wkr_bf, wvu_bf,
        bq_up, bk_nope, bk_rope, bv_up, qb, kb, krp, vt);

    // ---- rope into kb[:,1024:2048) ----
    rope_bf<<<dim3(M, 2), 256, 0, stream>>>(krp, kb);

    // ---- attention: 512 threads, 8 waves x 16 q-rows, swapped QK^T ----
    attn_mfma<<<dim3(S_ / 128, B_ * NH_), 512, 0, stream>>>(qb, kb, vt, ob);

    // ---- output projection (fp32 out): BN=64, 1024 blocks ----
    gemm_out<<<dim3(32, 32), 256, 0, stream>>>(ob, wo_bf, bo, out);
}

// Round 8
// 374.161 us; speedup vs baseline: 8.5393x; 1.0168x over previous
//
#include <hip/hip_runtime.h>
#include <math.h>

#define B_  2
#define S_  2048
#define H_  2048
#define NH_ 16
#define HD_ 128

typedef __attribute__((ext_vector_type(8))) short short8;
typedef __attribute__((ext_vector_type(4))) float f32x4;

#define AS1 __attribute__((address_space(1)))
#define AS3 __attribute__((address_space(3)))

// 1/sqrt(128) * log2(e)  (softmax runs in exp2 domain)
#define QSCALE_LOG2 (0.08838834764831845f * 1.4426950408889634f)

__device__ __forceinline__ ushort f2bf(float f) {
    union { float f; unsigned u; } x; x.f = f;
    unsigned r = (x.u + 0x7FFF + ((x.u >> 16) & 1)) >> 16;
    return (ushort)r;
}
__device__ __forceinline__ float bf2f(ushort u) {
    union { unsigned u; float f; } x; x.u = ((unsigned)u) << 16;
    return x.f;
}
__device__ __forceinline__ unsigned cvt_pk_bf16(float a, float b) {
    unsigned r;  // D[15:0]=bf16(S0)=a, D[31:16]=bf16(S1)=b
    asm("v_cvt_pk_bf16_f32 %0, %1, %2" : "=v"(r) : "v"(a), "v"(b));
    return r;
}
__device__ __forceinline__ void gload_lds16(const void* g, void* l) {
    __builtin_amdgcn_global_load_lds((const AS1 void*)g, (AS3 void*)l, 16, 0, 0);
}

// ---------------------------------------------------------------------------
// Fused fp32 -> bf16 cast over 8 segments
// ---------------------------------------------------------------------------
struct CastSeg { const float* src; ushort* dst; unsigned n4; };
struct CastParams { CastSeg seg[8]; unsigned total4; };

__global__ __launch_bounds__(256)
void cast_all(CastParams p)
{
    unsigned i = blockIdx.x * 256 + threadIdx.x;   // float4 index
    if (i >= p.total4) return;
#pragma unroll
    for (int s = 0; s < 8; ++s) {
        if (i < p.seg[s].n4) {
            const float4 v = reinterpret_cast<const float4*>(p.seg[s].src)[i];
            ushort4 o;
            o.x = f2bf(v.x); o.y = f2bf(v.y); o.z = f2bf(v.z); o.w = f2bf(v.w);
            reinterpret_cast<ushort4*>(p.seg[s].dst)[i] = o;
            return;
        }
        i -= p.seg[s].n4;
    }
}

// ---------------------------------------------------------------------------
// Merged DOWN projection, BK=64: both latents, N=1024 (cols 0..511 -> lat_q,
// 512..1023 -> lat_kv). BM=128, BN=64. 4 waves stacked along M; 16 MFMA per
// wave per K-step. Grid (16,32)=512 blocks.
// ---------------------------------------------------------------------------
__global__ __launch_bounds__(256)
void gemm_down(const ushort* __restrict__ hs,
               const ushort* __restrict__ wqd, const ushort* __restrict__ wkvd,
               const float* __restrict__ bqd, const float* __restrict__ bkvd,
               ushort* __restrict__ latq, ushort* __restrict__ latkv)
{
    constexpr int K = 2048;
    __shared__ ushort Asm[128 * 64];   // [row][64] linear, 128B rows
    __shared__ ushort Bsm[64 * 64];

    const int tid  = threadIdx.x;
    const int w    = tid >> 6;
    const int lane = tid & 63;
    const int lo   = lane & 15;
    const int hi   = lane >> 4;
    const int m0   = blockIdx.y * 128;
    const int n0   = blockIdx.x * 64;
    const int lr8  = lane >> 3;        // row within 8-row chunk
    const int lc8  = (lane & 7) * 8;   // ushort col within 64-col row

    const int seg = n0 >> 9;
    const int nl  = n0 & 511;
    const ushort* W    = (seg ? wkvd : wqd) + (size_t)nl * K;
    const float*  bias = (seg ? bkvd : bqd) + nl;
    ushort*       outp = seg ? latkv : latq;

    f32x4 acc[2][4];
#pragma unroll
    for (int i = 0; i < 2; ++i)
#pragma unroll
        for (int j = 0; j < 4; ++j) acc[i][j] = f32x4{0.f, 0.f, 0.f, 0.f};

    for (int k0 = 0; k0 < K; k0 += 64) {
        __syncthreads();
#pragma unroll
        for (int t = 0; t < 4; ++t) {           // A: 16 chunks of 8 rows
            const int c = w * 4 + t;
            gload_lds16(hs + (size_t)(m0 + c * 8 + lr8) * K + k0 + lc8,
                        (char*)Asm + c * 1024);
        }
#pragma unroll
        for (int t = 0; t < 2; ++t) {           // W: 8 chunks
            const int c = w * 2 + t;
            gload_lds16(W + (size_t)(c * 8 + lr8) * K + k0 + lc8,
                        (char*)Bsm + c * 1024);
        }
        __syncthreads();

#pragma unroll
        for (int ks = 0; ks < 2; ++ks) {
            short8 a[2], b[4];
#pragma unroll
            for (int i = 0; i < 2; ++i)
                a[i] = *reinterpret_cast<const short8*>(
                    &Asm[(w * 32 + i * 16 + lo) * 64 + ks * 32 + hi * 8]);
#pragma unroll
            for (int j = 0; j < 4; ++j)
                b[j] = *reinterpret_cast<const short8*>(
                    &Bsm[(j * 16 + lo) * 64 + ks * 32 + hi * 8]);
#pragma unroll
            for (int i = 0; i < 2; ++i)
#pragma unroll
                for (int j = 0; j < 4; ++j)
                    acc[i][j] = __builtin_amdgcn_mfma_f32_16x16x32_bf16(a[i], b[j], acc[i][j], 0, 0, 0);
        }
    }

#pragma unroll
    for (int j = 0; j < 4; ++j) {
        const int col = j * 16 + lo;
        const float bv = bias[col];
#pragma unroll
        for (int i = 0; i < 2; ++i) {
            const int row0 = m0 + w * 32 + i * 16 + hi * 4;
#pragma unroll
            for (int r = 0; r < 4; ++r)
                outp[(size_t)(row0 + r) * 512 + nl + col] = f2bf(acc[i][j][r] + bv);
        }
    }
}

// ---------------------------------------------------------------------------
// Merged UP projection, BK=64: N = 6144, K = 512.
//   [0,2048)    : q  -> qb (scaled by QSCALE_LOG2, mode 2)
//   [2048,3072) : k_nope -> kb
//   [3072,4096) : k_rope(pre) -> krp
//   [4096,6144) : v  -> vt transposed [bh][d][tok] (mode 3)
// BM=BN=128, 2x2 waves, 32 MFMA per wave per K-step. Grid (48,32)=1536.
// ---------------------------------------------------------------------------
__global__ __launch_bounds__(256)
void gemm_up(const ushort* __restrict__ latq, const ushort* __restrict__ latkv,
             const ushort* __restrict__ wqu, const ushort* __restrict__ wkn,
             const ushort* __restrict__ wkr, const ushort* __restrict__ wvu,
             const float* __restrict__ bq, const float* __restrict__ bkn,
             const float* __restrict__ bkr, const float* __restrict__ bv,
             ushort* __restrict__ qb, ushort* __restrict__ kb,
             ushort* __restrict__ krp, ushort* __restrict__ vt)
{
    constexpr int K = 512;
    __shared__ ushort Asm[128 * 64];
    __shared__ ushort Bsm[128 * 64];

    const int tid  = threadIdx.x;
    const int w    = tid >> 6;
    const int lane = tid & 63;
    const int lo   = lane & 15;
    const int hi   = lane >> 4;
    const int wm   = w >> 1;
    const int wn   = w & 1;
    const int m0   = blockIdx.y * 128;
    const int n0   = blockIdx.x * 128;
    const int lr8  = lane >> 3;
    const int lc8  = (lane & 7) * 8;

    const ushort* A;  const ushort* W;  const float* bias;
    ushort* outp = nullptr;  int ldc = 0;  int ncol0;  int mode;
    if (n0 < 2048)      { A = latq;  W = wqu + (size_t)n0 * K;          bias = bq  + n0;
                          outp = qb;  ldc = 2048; ncol0 = n0;        mode = 2; }
    else if (n0 < 3072) { A = latkv; W = wkn + (size_t)(n0 - 2048) * K; bias = bkn + (n0 - 2048);
                          outp = kb;  ldc = 2048; ncol0 = n0 - 2048; mode = 1; }
    else if (n0 < 4096) { A = latkv; W = wkr + (size_t)(n0 - 3072) * K; bias = bkr + (n0 - 3072);
                          outp = krp; ldc = 1024; ncol0 = n0 - 3072; mode = 1; }
    else                { A = latkv; W = wvu + (size_t)(n0 - 4096) * K; bias = bv  + (n0 - 4096);
                          outp = vt;  ldc = 0;    ncol0 = n0 - 4096; mode = 3; }

    f32x4 acc[4][4];
#pragma unroll
    for (int i = 0; i < 4; ++i)
#pragma unroll
        for (int j = 0; j < 4; ++j) acc[i][j] = f32x4{0.f, 0.f, 0.f, 0.f};

    for (int k0 = 0; k0 < K; k0 += 64) {
        __syncthreads();
#pragma unroll
        for (int t = 0; t < 4; ++t) {
            const int c = w * 4 + t;
            gload_lds16(A + (size_t)(m0 + c * 8 + lr8) * K + k0 + lc8,
                        (char*)Asm + c * 1024);
            gload_lds16(W + (size_t)(c * 8 + lr8) * K + k0 + lc8,
                        (char*)Bsm + c * 1024);
        }
        __syncthreads();

#pragma unroll
        for (int ks = 0; ks < 2; ++ks) {
            short8 a[4], b[4];
#pragma unroll
            for (int i = 0; i < 4; ++i)
                a[i] = *reinterpret_cast<const short8*>(
                    &Asm[(wm * 64 + i * 16 + lo) * 64 + ks * 32 + hi * 8]);
#pragma unroll
            for (int j = 0; j < 4; ++j)
                b[j] = *reinterpret_cast<const short8*>(
                    &Bsm[(wn * 64 + j * 16 + lo) * 64 + ks * 32 + hi * 8]);
#pragma unroll
            for (int i = 0; i < 4; ++i)
#pragma unroll
                for (int j = 0; j < 4; ++j)
                    acc[i][j] = __builtin_amdgcn_mfma_f32_16x16x32_bf16(a[i], b[j], acc[i][j], 0, 0, 0);
        }
    }

#pragma unroll
    for (int j = 0; j < 4; ++j) {
        const int col = wn * 64 + j * 16 + lo;
        const float bb = bias[col];
#pragma unroll
        for (int i = 0; i < 4; ++i) {
            const int row0 = m0 + wm * 64 + i * 16 + hi * 4;
            if (mode == 3) {
                const int gcol = ncol0 + col;
                const int hh = gcol >> 7, dd = gcol & 127;
                const int bbi = row0 >> 11, sidx = row0 & 2047;
                ushort4 o;
                o.x = f2bf(acc[i][j][0] + bb);
                o.y = f2bf(acc[i][j][1] + bb);
                o.z = f2bf(acc[i][j][2] + bb);
                o.w = f2bf(acc[i][j][3] + bb);
                *reinterpret_cast<ushort4*>(
                    vt + (((size_t)(bbi * 16 + hh) * 128 + dd) << 11) + sidx) = o;
            } else if (mode == 2) {
#pragma unroll
                for (int r = 0; r < 4; ++r)
                    outp[(size_t)(row0 + r) * ldc + ncol0 + col] =
                        f2bf((acc[i][j][r] + bb) * QSCALE_LOG2);
            } else {
#pragma unroll
                for (int r = 0; r < 4; ++r)
                    outp[(size_t)(row0 + r) * ldc + ncol0 + col] =
                        f2bf(acc[i][j][r] + bb);
            }
        }
    }
}

// ---------------------------------------------------------------------------
// Output projection, BK=64: out(f32) = ob @ Wo^T + bo.  BM=BN=128, K=2048.
// Grid (16, 32) = 512 blocks (2/CU), 32 MFMA per wave per K-step.
// ---------------------------------------------------------------------------
__global__ __launch_bounds__(256)
void gemm_out(const ushort* __restrict__ A, const ushort* __restrict__ W,
              const float* __restrict__ bias, float* __restrict__ C)
{
    constexpr int K = 2048;
    __shared__ ushort Asm[128 * 64];
    __shared__ ushort Bsm[128 * 64];

    const int tid  = threadIdx.x;
    const int w    = tid >> 6;
    const int lane = tid & 63;
    const int lo   = lane & 15;
    const int hi   = lane >> 4;
    const int wm   = w >> 1;
    const int wn   = w & 1;
    const int m0   = blockIdx.y * 128;
    const int n0   = blockIdx.x * 128;
    const int lr8  = lane >> 3;
    const int lc8  = (lane & 7) * 8;

    f32x4 acc[4][4];
#pragma unroll
    for (int i = 0; i < 4; ++i)
#pragma unroll
        for (int j = 0; j < 4; ++j) acc[i][j] = f32x4{0.f, 0.f, 0.f, 0.f};

    for (int k0 = 0; k0 < K; k0 += 64) {
        __syncthreads();
#pragma unroll
        for (int t = 0; t < 4; ++t) {
            const int c = w * 4 + t;
            gload_lds16(A + (size_t)(m0 + c * 8 + lr8) * K + k0 + lc8,
                        (char*)Asm + c * 1024);
            gload_lds16(W + (size_t)(n0 + c * 8 + lr8) * K + k0 + lc8,
                        (char*)Bsm + c * 1024);
        }
        __syncthreads();

#pragma unroll
        for (int ks = 0; ks < 2; ++ks) {
            short8 a[4], b[4];
#pragma unroll
            for (int i = 0; i < 4; ++i)
                a[i] = *reinterpret_cast<const short8*>(
                    &Asm[(wm * 64 + i * 16 + lo) * 64 + ks * 32 + hi * 8]);
#pragma unroll
            for (int j = 0; j < 4; ++j)
                b[j] = *reinterpret_cast<const short8*>(
                    &Bsm[(wn * 64 + j * 16 + lo) * 64 + ks * 32 + hi * 8]);
#pragma unroll
            for (int i = 0; i < 4; ++i)
#pragma unroll
                for (int j = 0; j < 4; ++j)
                    acc[i][j] = __builtin_amdgcn_mfma_f32_16x16x32_bf16(a[i], b[j], acc[i][j], 0, 0, 0);
        }
    }

#pragma unroll
    for (int j = 0; j < 4; ++j) {
        const int col = n0 + wn * 64 + j * 16 + lo;
        const float bb = bias[col];
#pragma unroll
        for (int i = 0; i < 4; ++i) {
            const int row0 = m0 + wm * 64 + i * 16 + hi * 4;
#pragma unroll
            for (int r = 0; r < 4; ++r)
                C[(size_t)(row0 + r) * 2048 + col] = acc[i][j][r] + bb;
        }
    }
}

// ---------------------------------------------------------------------------
// RoPE: pre-rotary k_rope (bf16 [4096][1024]) -> kb cols [1024,2048).
// ---------------------------------------------------------------------------
__global__ void rope_bf(const ushort* __restrict__ pre, ushort* __restrict__ kb)
{
    const int row = blockIdx.x;
    const int d   = blockIdx.y * 256 + threadIdx.x;   // 0..511
    const int pos = row & (S_ - 1);
    const float inv = expf((float)d * -0.017988946f); // ln(10000)/512
    const float ang = (float)pos * inv;
    const float c = cosf(ang), s = sinf(ang);
    const float x1 = bf2f(pre[(size_t)row * 1024 + d]);
    const float x2 = bf2f(pre[(size_t)row * 1024 + 512 + d]);
    kb[(size_t)row * 2048 + 1024 + d]       = f2bf(x1 * c - x2 * s);
    kb[(size_t)row * 2048 + 1024 + 512 + d] = f2bf(x1 * s + x2 * c);
}

// ---------------------------------------------------------------------------
// Flash attention, bf16 MFMA, swapped QK^T (unchanged from round 7).
// ---------------------------------------------------------------------------
__global__ __launch_bounds__(512)
void attn_mfma(const ushort* __restrict__ Q, const ushort* __restrict__ K,
               const ushort* __restrict__ Vt, ushort* __restrict__ O)
{
    __shared__ ushort Kl[64 * 128];     // 16 KB, swizzled 256B rows
    __shared__ ushort Vl[128 * 72];     // 18 KB, [d][k] padded
    __shared__ ushort Pl[8 * 16 * 72];  // 18 KB, per-wave 16 rows

    const int tid  = threadIdx.x;
    const int w    = tid >> 6;          // 0..7
    const int lane = tid & 63;
    const int lo   = lane & 15;
    const int hi   = lane >> 4;
    const int bh   = blockIdx.y;
    const int b    = bh >> 4;
    const int q0   = blockIdx.x * 128;
    const size_t headoff = (size_t)(bh & 15) * HD_;

    // Q fragments (pre-scaled by 1/sqrt(128)*log2e); lane lo = q-row.
    short8 aq[4];
    {
        const ushort* qrow = Q + (size_t)(b * S_ + q0 + w * 16 + lo) * H_ + headoff;
#pragma unroll
        for (int kd = 0; kd < 4; ++kd)
            aq[kd] = *reinterpret_cast<const short8*>(qrow + kd * 32 + hi * 8);
    }

    f32x4 oacc[8];
#pragma unroll
    for (int fd = 0; fd < 8; ++fd) oacc[fd] = f32x4{0.f, 0.f, 0.f, 0.f};
    float m_run = -INFINITY, l_run = 0.f;      // for q-row = lo

    const ushort* kbase = K  + (size_t)(b * S_) * H_ + headoff;
    const ushort* vbase = Vt + (size_t)bh * 128 * S_;

    short8 kst[2], vst[2];
    auto issue_loads = [&](int kt) {
#pragma unroll
        for (int r = 0; r < 2; ++r) {
            const int c = r * 512 + tid;       // 0..1023 16B chunks
            kst[r] = *reinterpret_cast<const short8*>(
                kbase + (size_t)(kt * 64 + (c >> 4)) * H_ + (c & 15) * 8);
            vst[r] = *reinterpret_cast<const short8*>(
                vbase + (size_t)(c >> 3) * S_ + kt * 64 + (c & 7) * 8);
        }
    };
    auto write_lds = [&]() {
#pragma unroll
        for (int r = 0; r < 2; ++r) {
            const int c = r * 512 + tid;
            const int key = c >> 4, slot = c & 15;
            *reinterpret_cast<short8*>(
                (char*)Kl + key * 256 + ((slot * 16) ^ ((key & 7) << 4))) = kst[r];
            *reinterpret_cast<short8*>(
                (char*)Vl + (c >> 3) * 144 + (c & 7) * 16) = vst[r];
        }
    };

    issue_loads(0);
    write_lds();
    __syncthreads();

    const int swz = (lo & 7) << 4;

    for (int kt = 0; kt < S_ / 64; ++kt) {
        if (kt + 1 < S_ / 64) issue_loads(kt + 1);   // in flight across compute

        // ---- S^T = K Q^T: st[fn][r] = P[key = fn*16 + hi*4 + r][q = lo] ----
        f32x4 st[4];
#pragma unroll
        for (int fn = 0; fn < 4; ++fn) st[fn] = f32x4{0.f, 0.f, 0.f, 0.f};

        __builtin_amdgcn_s_setprio(1);
#pragma unroll
        for (int fn = 0; fn < 4; ++fn) {
            const int kbyte = (fn * 16 + lo) * 256;
#pragma unroll
            for (int kd = 0; kd < 4; ++kd) {
                short8 bk = *reinterpret_cast<const short8*>(
                    (const char*)Kl + kbyte + ((kd * 64 + hi * 16) ^ swz));
                st[fn] = __builtin_amdgcn_mfma_f32_16x16x32_bf16(bk, aq[kd], st[fn], 0, 0, 0);
            }
        }
        __builtin_amdgcn_s_setprio(0);

        // ---- softmax for q = lo (16 local keys, then cross-hi combine) ----
        float mx = st[0][0];
#pragma unroll
        for (int fn = 0; fn < 4; ++fn)
#pragma unroll
            for (int r = 0; r < 4; ++r) mx = fmaxf(mx, st[fn][r]);
        mx = fmaxf(mx, __shfl_xor(mx, 16));
        mx = fmaxf(mx, __shfl_xor(mx, 32));

        float fscale = 1.0f;
        bool resc = false;
        if (mx > m_run + 8.0f) {            // defer-max (T13, log2 domain)
            fscale = exp2f(m_run - mx);
            m_run = mx;
            resc = true;
        }

        float p[4][4];
        float ls = 0.f;
#pragma unroll
        for (int fn = 0; fn < 4; ++fn)
#pragma unroll
            for (int r = 0; r < 4; ++r) {
                p[fn][r] = exp2f(st[fn][r] - m_run);
                ls += p[fn][r];
            }
        ls += __shfl_xor(ls, 16);
        ls += __shfl_xor(ls, 32);
        l_run = l_run * fscale + ls;

        // ---- pack P (bf16) and write 4 x b64: keys fn*16+hi*4..+3, row lo --
        {
            char* prow = (char*)Pl + (w * 16 + lo) * 144 + hi * 8;
#pragma unroll
            for (int fn = 0; fn < 4; ++fn) {
                uint2 u;
                u.x = cvt_pk_bf16(p[fn][0], p[fn][1]);
                u.y = cvt_pk_bf16(p[fn][2], p[fn][3]);
                *reinterpret_cast<uint2*>(prow + fn * 32) = u;
            }
        }

        // ---- rescale O (rows hi*4+r; factors live in lanes hi*4+r) ----
        if (__any((int)resc)) {
#pragma unroll
            for (int r = 0; r < 4; ++r) {
                const float fr = __shfl(fscale, hi * 4 + r);
#pragma unroll
                for (int fd = 0; fd < 8; ++fd) oacc[fd][r] *= fr;
            }
        }

        // ---- O += P V ----
        __builtin_amdgcn_s_setprio(1);
#pragma unroll
        for (int ks = 0; ks < 2; ++ks) {
            short8 pa = *reinterpret_cast<const short8*>(
                (const char*)Pl + (w * 16 + lo) * 144 + ks * 64 + hi * 16);
#pragma unroll
            for (int fd = 0; fd < 8; ++fd) {
                short8 bv = *reinterpret_cast<const short8*>(
                    (const char*)Vl + (fd * 16 + lo) * 144 + ks * 64 + hi * 16);
                oacc[fd] = __builtin_amdgcn_mfma_f32_16x16x32_bf16(pa, bv, oacc[fd], 0, 0, 0);
            }
        }
        __builtin_amdgcn_s_setprio(0);

        __syncthreads();                 // all waves done reading Kl/Vl
        if (kt + 1 < S_ / 64) {
            write_lds();                 // vmcnt wait inserted by compiler
            __syncthreads();
        }
    }

    // ---- normalize + store bf16 (l for row x lives in lane x) ----
#pragma unroll
    for (int r = 0; r < 4; ++r) {
        const float lr  = __shfl(l_run, hi * 4 + r);
        const float inv = 1.0f / lr;
        ushort* orow = O + (size_t)(b * S_ + q0 + w * 16 + hi * 4 + r) * H_
                         + headoff + lo;
#pragma unroll
        for (int fd = 0; fd < 8; ++fd)
            orow[fd * 16] = f2bf(oacc[fd][r] * inv);
    }
}

// ---------------------------------------------------------------------------
// Launch
// ---------------------------------------------------------------------------
extern "C" void kernel_launch(void* const* d_in, const int* in_sizes, int n_in,
                              void* d_out, int out_size, void* d_ws, size_t ws_size,
                              hipStream_t stream)
{
    const float* hs       = (const float*)d_in[0];
    const float* Wq_down  = (const float*)d_in[1];
    const float* bq_down  = (const float*)d_in[2];
    const float* Wkv_down = (const float*)d_in[3];
    const float* bkv_down = (const float*)d_in[4];
    const float* Wq_up    = (const float*)d_in[5];
    const float* bq_up    = (const float*)d_in[6];
    const float* Wk_nope  = (const float*)d_in[7];
    const float* bk_nope  = (const float*)d_in[8];
    const float* Wk_rope  = (const float*)d_in[9];
    const float* bk_rope  = (const float*)d_in[10];
    const float* Wv_up    = (const float*)d_in[11];
    const float* bv_up    = (const float*)d_in[12];
    const float* Wo       = (const float*)d_in[13];
    const float* bo       = (const float*)d_in[14];
    float* out = (float*)d_out;

    // Workspace layout in ushort (bf16) units. Total ~120 MB.
    ushort* ws = (ushort*)d_ws;
    ushort* hs_bf   = ws;                                // 8,388,608
    ushort* wqd_bf  = hs_bf  + (size_t)8388608;          // 1,048,576
    ushort* wkvd_bf = wqd_bf + (size_t)1048576;          // 1,048,576
    ushort* wqu_bf  = wkvd_bf+ (size_t)1048576;          // 1,048,576
    ushort* wkn_bf  = wqu_bf + (size_t)1048576;          //   524,288
    ushort* wkr_bf  = wkn_bf + (size_t)524288;           //   524,288
    ushort* wvu_bf  = wkr_bf + (size_t)524288;           // 1,048,576
    ushort* wo_bf   = wvu_bf + (size_t)1048576;          // 4,194,304
    ushort* lat_q   = wo_bf  + (size_t)4194304;          // 2,097,152
    ushort* lat_kv  = lat_q  + (size_t)2097152;          // 2,097,152
    ushort* qb      = lat_kv + (size_t)2097152;          // 8,388,608
    ushort* kb      = qb     + (size_t)8388608;          // 8,388,608
    ushort* krp     = kb     + (size_t)8388608;          // 4,194,304
    ushort* vt      = krp    + (size_t)4194304;          // 8,388,608
    ushort* ob      = vt     + (size_t)8388608;          // 8,388,608

    const int M = B_ * S_;   // 4096

    // ---- fused casts (1 launch) ----
    CastParams cp;
    cp.seg[0] = { hs,       hs_bf,   8388608u / 4 };
    cp.seg[1] = { Wq_down,  wqd_bf,  1048576u / 4 };
    cp.seg[2] = { Wkv_down, wkvd_bf, 1048576u / 4 };
    cp.seg[3] = { Wq_up,    wqu_bf,  1048576u / 4 };
    cp.seg[4] = { Wk_nope,  wkn_bf,   524288u / 4 };
    cp.seg[5] = { Wk_rope,  wkr_bf,   524288u / 4 };
    cp.seg[6] = { Wv_up,    wvu_bf,  1048576u / 4 };
    cp.seg[7] = { Wo,       wo_bf,   4194304u / 4 };
    cp.total4 = (8388608u + 1048576u * 4 + 524288u * 2 + 4194304u) / 4;
    cast_all<<<(cp.total4 + 255) / 256, 256, 0, stream>>>(cp);

    // ---- merged down projections: N=1024, K=2048, BK=64, 512 blocks ----
    gemm_down<<<dim3(16, 32), 256, 0, stream>>>(
        hs_bf, wqd_bf, wkvd_bf, bq_down, bkv_down, lat_q, lat_kv);

    // ---- merged up projections: N=6144, K=512, BK=64, 1536 blocks ----
    gemm_up<<<dim3(48, 32), 256, 0, stream>>>(
        lat_q, lat_kv, wqu_bf, wkn_bf, wkr_bf, wvu_bf,
        bq_up, bk_nope, bk_rope, bv_up, qb, kb, krp, vt);

    // ---- rope into kb[:,1024:2048) ----
    rope_bf<<<dim3(M, 2), 256, 0, stream>>>(krp, kb);

    // ---- attention: 512 threads, 8 waves x 16 q-rows, swapped QK^T ----
    attn_mfma<<<dim3(S_ / 128, B_ * NH_), 512, 0, stream>>>(qb, kb, vt, ob);

    // ---- output projection (fp32 out): BM=BN=128, BK=64, 512 blocks ----
    gemm_out<<<dim3(16, 32), 256, 0, stream>>>(ob, wo_bf, bo, out);
}